// Round 2
// baseline (3720.503 us; speedup 1.0000x reference)
//
#include <hip/hip_runtime.h>
#include <math.h>

#define N_NODES 50000
#define N_EDGES 800000
#define N_GRAPH 2000
#define F_INPUT 34
#define HID 256
#define NLAYER 5

// ---------- helpers ----------
__device__ __forceinline__ float gelu_f(float x) {
  return 0.5f * x * (1.0f + erff(x * 0.70710678118654752440f));
}
// monotonic float->uint mapping for atomicMax
__device__ __forceinline__ unsigned fkey(float f) {
  unsigned u = __float_as_uint(f);
  return (u & 0x80000000u) ? ~u : (u | 0x80000000u);
}
__device__ __forceinline__ float funkey(unsigned k) {
  unsigned u = (k & 0x80000000u) ? (k ^ 0x80000000u) : ~k;
  return __uint_as_float(u);
}
#define MAXKEY_INIT 0x007FFFFFu   // fkey(-inf)

// ---------- GEMM: C[M,Nn] = A[M,K] @ B[K,Nn] + bias (+C if accum) ----------
__global__ __launch_bounds__(256) void gemm_bias(
    const float* __restrict__ A, const float* __restrict__ B,
    const float* __restrict__ bias, float* __restrict__ C,
    int M, int Nn, int K, int accum) {
  __shared__ float As[16][64];
  __shared__ float Bs[16][64];
  int tid = threadIdx.x;
  int tx = tid & 15, ty = tid >> 4;
  int row0 = blockIdx.y * 64;
  int col0 = blockIdx.x * 64;
  float acc[4][4] = {};
  int a_r = tid >> 2;          // 0..63 (row within tile)
  int a_c = (tid & 3) * 4;     // k offset 0,4,8,12
  int b_r = tid >> 4;          // 0..15 (k)
  int b_c = (tid & 15) * 4;    // col

  for (int k0 = 0; k0 < K; k0 += 16) {
    int ar = row0 + a_r;
#pragma unroll
    for (int i = 0; i < 4; ++i) {
      int kc = k0 + a_c + i;
      As[a_c + i][a_r] = (ar < M && kc < K) ? A[(long)ar * K + kc] : 0.f;
    }
    int bk = k0 + b_r;
    if (bk < K) {
      float4 bv = *(const float4*)&B[(long)bk * Nn + col0 + b_c];
      Bs[b_r][b_c + 0] = bv.x; Bs[b_r][b_c + 1] = bv.y;
      Bs[b_r][b_c + 2] = bv.z; Bs[b_r][b_c + 3] = bv.w;
    } else {
      Bs[b_r][b_c + 0] = 0.f; Bs[b_r][b_c + 1] = 0.f;
      Bs[b_r][b_c + 2] = 0.f; Bs[b_r][b_c + 3] = 0.f;
    }
    __syncthreads();
#pragma unroll
    for (int kk = 0; kk < 16; ++kk) {
      float4 a = *(const float4*)&As[kk][ty * 4];
      float4 b = *(const float4*)&Bs[kk][tx * 4];
      float av[4] = {a.x, a.y, a.z, a.w};
      float bv[4] = {b.x, b.y, b.z, b.w};
#pragma unroll
      for (int i = 0; i < 4; ++i)
#pragma unroll
        for (int j = 0; j < 4; ++j) acc[i][j] += av[i] * bv[j];
    }
    __syncthreads();
  }
  float4 bi = *(const float4*)&bias[col0 + tx * 4];
  float bia[4] = {bi.x, bi.y, bi.z, bi.w};
#pragma unroll
  for (int i = 0; i < 4; ++i) {
    int r = row0 + ty * 4 + i;
    if (r < M) {
      float4* cp = (float4*)&C[(long)r * Nn + col0 + tx * 4];
      float4 o;
      o.x = acc[i][0] + bia[0]; o.y = acc[i][1] + bia[1];
      o.z = acc[i][2] + bia[2]; o.w = acc[i][3] + bia[3];
      if (accum) {
        float4 old = *cp;
        o.x += old.x; o.y += old.y; o.z += old.z; o.w += old.w;
      }
      *cp = o;
    }
  }
}

// ---------- LayerNorm (+pre-bias) (+GELU) (+residual) ; one wave per row ----------
__global__ __launch_bounds__(256) void ln_act(
    const float* __restrict__ in, const float* __restrict__ pre_bias,
    const float* __restrict__ res, const float* __restrict__ gam,
    const float* __restrict__ bet, float* __restrict__ out,
    int n_rows, int width, int do_gelu) {
  int wid = blockIdx.x * 4 + (threadIdx.x >> 6);
  int lane = threadIdx.x & 63;
  if (wid >= n_rows) return;
  int chunks = width >> 8;   // 256 -> 1, 512 -> 2
  float4 v[2];
  float s = 0.f;
  for (int c = 0; c < chunks; ++c) {
    int off = c * 256 + lane * 4;
    float4 t = *(const float4*)&in[(size_t)wid * width + off];
    if (pre_bias) {
      float4 pb = *(const float4*)&pre_bias[off];
      t.x += pb.x; t.y += pb.y; t.z += pb.z; t.w += pb.w;
    }
    v[c] = t;
    s += t.x + t.y + t.z + t.w;
  }
  for (int o = 1; o < 64; o <<= 1) s += __shfl_xor(s, o);
  float mean = s / (float)width;
  float vs = 0.f;
  for (int c = 0; c < chunks; ++c) {
    float dx = v[c].x - mean, dy = v[c].y - mean, dz = v[c].z - mean, dw = v[c].w - mean;
    vs += dx * dx + dy * dy + dz * dz + dw * dw;
  }
  for (int o = 1; o < 64; o <<= 1) vs += __shfl_xor(vs, o);
  float inv = rsqrtf(vs / (float)width + 1e-5f);
  for (int c = 0; c < chunks; ++c) {
    int off = c * 256 + lane * 4;
    float4 g4 = *(const float4*)&gam[off];
    float4 b4 = *(const float4*)&bet[off];
    float y[4] = {(v[c].x - mean) * inv * g4.x + b4.x,
                  (v[c].y - mean) * inv * g4.y + b4.y,
                  (v[c].z - mean) * inv * g4.z + b4.z,
                  (v[c].w - mean) * inv * g4.w + b4.w};
    if (do_gelu) {
#pragma unroll
      for (int i = 0; i < 4; ++i) y[i] = gelu_f(y[i]);
    }
    size_t idx = (size_t)wid * width + off;
    if (res) {
      float4 r4 = *(const float4*)&res[idx];
      y[0] += r4.x; y[1] += r4.y; y[2] += r4.z; y[3] += r4.w;
    }
    float4 o4 = {y[0], y[1], y[2], y[3]};
    *(float4*)&out[idx] = o4;
  }
}

// ---------- CSR build ----------
__global__ __launch_bounds__(256) void edge_count(const int* __restrict__ ei,
                                                  int* __restrict__ counts) {
  int e = blockIdx.x * 256 + threadIdx.x;
  if (e < N_EDGES) atomicAdd(&counts[ei[N_EDGES + e]], 1);
}

__global__ __launch_bounds__(1024) void scan_counts(const int* __restrict__ counts,
                                                    int* __restrict__ indptr,
                                                    int* __restrict__ cursor, int n) {
  __shared__ int sm[1024];
  __shared__ int carry;
  int tid = threadIdx.x;
  if (tid == 0) carry = 0;
  __syncthreads();
  for (int base = 0; base < n; base += 1024) {
    int i = base + tid;
    int v = (i < n) ? counts[i] : 0;
    sm[tid] = v;
    __syncthreads();
    for (int off = 1; off < 1024; off <<= 1) {
      int t = (tid >= off) ? sm[tid - off] : 0;
      __syncthreads();
      sm[tid] += t;
      __syncthreads();
    }
    int excl = sm[tid] - v + carry;
    if (i < n) { indptr[i] = excl; cursor[i] = excl; }
    int total = sm[1023];
    __syncthreads();
    if (tid == 0) carry += total;
    __syncthreads();
  }
  if (tid == 0) indptr[n] = carry;
}

__global__ __launch_bounds__(256) void edge_scatter(const int* __restrict__ ei,
                                                    int* __restrict__ cursor,
                                                    int* __restrict__ esrc) {
  int e = blockIdx.x * 256 + threadIdx.x;
  if (e < N_EDGES) {
    int d = ei[N_EDGES + e];
    int p = atomicAdd(&cursor[d], 1);
    esrc[p] = ei[e];
  }
}

// ---------- GATv2 edge aggregation: one wave per destination node ----------
// includes implicit self loop. out may alias xr (xr row i is read only by wave i,
// before any write of out row i).
__global__ __launch_bounds__(256) void gat_agg(
    const float* __restrict__ xl, const float* __restrict__ xr,
    const float* __restrict__ att, const int* __restrict__ indptr,
    const int* __restrict__ esrc, float* __restrict__ out) {
  int wid = blockIdx.x * 4 + (threadIdx.x >> 6);
  int lane = threadIdx.x & 63;
  if (wid >= N_NODES) return;
  float4 xri = *(const float4*)&xr[(size_t)wid * HID + lane * 4];
  float4 a4 = *(const float4*)&att[lane * 4];  // (h = lane>>3, d = (lane&7)*4)
  int beg = indptr[wid], end = indptr[wid + 1];
  float m = -INFINITY, lsum = 0.f;
  float ax = 0.f, ay = 0.f, az = 0.f, aw = 0.f;
  for (int e = beg - 1; e < end; ++e) {
    int j = (e < beg) ? wid : esrc[e];
    float4 xlj = *(const float4*)&xl[(size_t)j * HID + lane * 4];
    float ex = xlj.x + xri.x; ex = ex > 0.f ? ex : 0.2f * ex;
    float ey = xlj.y + xri.y; ey = ey > 0.f ? ey : 0.2f * ey;
    float ez = xlj.z + xri.z; ez = ez > 0.f ? ez : 0.2f * ez;
    float ew = xlj.w + xri.w; ew = ew > 0.f ? ew : 0.2f * ew;
    float p = ex * a4.x + ey * a4.y + ez * a4.z + ew * a4.w;
    p += __shfl_xor(p, 1); p += __shfl_xor(p, 2); p += __shfl_xor(p, 4);
    float sc = p;  // per-head score, same on the 8 lanes of the head
    if (sc > m) {
      float f = expf(m - sc);   // exp(-inf)=0 on first edge
      ax *= f; ay *= f; az *= f; aw *= f; lsum *= f;
      m = sc;
    }
    float w = expf(sc - m);
    ax += w * xlj.x; ay += w * xlj.y; az += w * xlj.z; aw += w * xlj.w;
    lsum += w;
  }
  float inv = 1.f / (lsum + 1e-16f);
  float4 o = {ax * inv, ay * inv, az * inv, aw * inv};
  *(float4*)&out[(size_t)wid * HID + lane * 4] = o;
}

// ---------- TransformerConv edge aggregation (no self loops) ----------
// out may alias q (q row i read only by wave i at start).
__global__ __launch_bounds__(256) void tr_agg(
    const float* __restrict__ q, const float* __restrict__ k,
    const float* __restrict__ v, const int* __restrict__ indptr,
    const int* __restrict__ esrc, float* __restrict__ out) {
  int wid = blockIdx.x * 4 + (threadIdx.x >> 6);
  int lane = threadIdx.x & 63;
  if (wid >= N_NODES) return;
  float4 qi = *(const float4*)&q[(size_t)wid * HID + lane * 4];
  int beg = indptr[wid], end = indptr[wid + 1];
  float m = -INFINITY, lsum = 0.f;
  float ax = 0.f, ay = 0.f, az = 0.f, aw = 0.f;
  const float scale = 0.17677669529663687f;  // 1/sqrt(32)
  for (int e = beg; e < end; ++e) {
    int j = esrc[e];
    float4 kj = *(const float4*)&k[(size_t)j * HID + lane * 4];
    float p = qi.x * kj.x + qi.y * kj.y + qi.z * kj.z + qi.w * kj.w;
    p += __shfl_xor(p, 1); p += __shfl_xor(p, 2); p += __shfl_xor(p, 4);
    float sc = p * scale;
    float4 vj = *(const float4*)&v[(size_t)j * HID + lane * 4];
    if (sc > m) {
      float f = expf(m - sc);
      ax *= f; ay *= f; az *= f; aw *= f; lsum *= f;
      m = sc;
    }
    float w = expf(sc - m);
    ax += w * vj.x; ay += w * vj.y; az += w * vj.z; aw += w * vj.w;
    lsum += w;
  }
  float inv = 1.f / (lsum + 1e-16f);   // empty segment -> 0
  float4 o = {ax * inv, ay * inv, az * inv, aw * inv};
  *(float4*)&out[(size_t)wid * HID + lane * 4] = o;
}

// ---------- pooling ----------
__global__ __launch_bounds__(256) void fill_u32(unsigned* __restrict__ p, unsigned val, int n) {
  int i = blockIdx.x * 256 + threadIdx.x;
  if (i < n) p[i] = val;
}

__global__ __launch_bounds__(256) void pool_scatter(
    const float* __restrict__ h, const int* __restrict__ batch,
    float* __restrict__ psum, unsigned* __restrict__ pmax, int* __restrict__ pcnt) {
  int t = blockIdx.x * 256 + threadIdx.x;
  int node = t >> 6;
  if (node >= N_NODES) return;
  int lane = t & 63;
  int g = batch[node];
  float4 vv = *(const float4*)&h[(size_t)node * HID + lane * 4];
  int base = g * HID + lane * 4;
  atomicAdd(&psum[base + 0], vv.x);
  atomicAdd(&psum[base + 1], vv.y);
  atomicAdd(&psum[base + 2], vv.z);
  atomicAdd(&psum[base + 3], vv.w);
  atomicMax(&pmax[base + 0], fkey(vv.x));
  atomicMax(&pmax[base + 1], fkey(vv.y));
  atomicMax(&pmax[base + 2], fkey(vv.z));
  atomicMax(&pmax[base + 3], fkey(vv.w));
  if (lane == 0) atomicAdd(&pcnt[g], 1);
}

__global__ __launch_bounds__(256) void pool_finalize(
    const float* __restrict__ psum, const unsigned* __restrict__ pmax,
    const int* __restrict__ pcnt, float* __restrict__ ge) {
  int t = blockIdx.x * 256 + threadIdx.x;
  if (t >= N_GRAPH * HID) return;
  int g = t >> 8, d = t & 255;
  float c = (float)max(pcnt[g], 1);
  ge[(size_t)g * 512 + d] = psum[t] / c;
  unsigned kk = pmax[t];
  ge[(size_t)g * 512 + 256 + d] = (kk == MAXKEY_INIT) ? 0.f : funkey(kk);
}

// ---------- host launch ----------
static inline void gemm_launch(const float* A, const float* B, const float* bias,
                               float* C, int M, int Nn, int K, int accum,
                               hipStream_t s) {
  dim3 grid(Nn / 64, (M + 63) / 64);
  gemm_bias<<<grid, 256, 0, s>>>(A, B, bias, C, M, Nn, K, accum);
}

extern "C" void kernel_launch(void* const* d_in, const int* in_sizes, int n_in,
                              void* d_out, int out_size, void* d_ws, size_t ws_size,
                              hipStream_t stream) {
  const float* x       = (const float*)d_in[0];
  const int*   ei      = (const int*)d_in[1];
  const int*   batch   = (const int*)d_in[2];
  const float* in_W    = (const float*)d_in[3];
  const float* in_b    = (const float*)d_in[4];
  const float* in_ln_g = (const float*)d_in[5];
  const float* in_ln_b = (const float*)d_in[6];
  const float* gat_Wl  = (const float*)d_in[7];
  const float* gat_bl  = (const float*)d_in[8];
  const float* gat_Wr  = (const float*)d_in[9];
  const float* gat_br  = (const float*)d_in[10];
  const float* gat_att = (const float*)d_in[11];
  const float* gat_bias= (const float*)d_in[12];
  const float* gat_ln_g= (const float*)d_in[13];
  const float* gat_ln_b= (const float*)d_in[14];
  const float* tr_Wq   = (const float*)d_in[15];
  const float* tr_bq   = (const float*)d_in[16];
  const float* tr_Wk   = (const float*)d_in[17];
  const float* tr_bk   = (const float*)d_in[18];
  const float* tr_Wv   = (const float*)d_in[19];
  const float* tr_bv   = (const float*)d_in[20];
  const float* tr_Wsk  = (const float*)d_in[21];
  const float* tr_bsk  = (const float*)d_in[22];
  const float* tr_ln_g = (const float*)d_in[23];
  const float* tr_ln_b = (const float*)d_in[24];
  const float* out_W   = (const float*)d_in[25];
  const float* out_b   = (const float*)d_in[26];
  const float* out_ln_g= (const float*)d_in[27];
  const float* out_ln_b= (const float*)d_in[28];

  // ---- workspace layout, every slice 256B-aligned ----
  char* w = (char*)d_ws;
  auto take = [&](size_t bytes) -> char* {
    char* p = w;
    w += (bytes + 255) & ~(size_t)255;
    return p;
  };
  const size_t NB = (size_t)N_NODES * HID * sizeof(float);  // 51.2 MB (mult of 256)
  float* h    = (float*)take(NB);
  float* bufA = (float*)take(NB);
  float* bufB = (float*)take(NB);
  float* bufC = (float*)take(NB);
  int* indptr = (int*)take((N_NODES + 1) * sizeof(int));
  int* cursor = (int*)take(N_NODES * sizeof(int));
  int* counts = (int*)take(N_NODES * sizeof(int));
  int* esrc   = (int*)take(N_EDGES * sizeof(int));
  // pool/output scratch overlays bufC (free after tr_agg; ~12.3MB < 51.2MB)
  {
    char* w2 = (char*)bufC;
    auto take2 = [&](size_t bytes) -> char* {
      char* p = w2;
      w2 += (bytes + 255) & ~(size_t)255;
      return p;
    };
    take2(1);  // keep bufC itself distinct? no — overlay is intended; see note below
    w2 = (char*)bufC;  // reset: overlay from start of bufC
    (void)take2;
  }
  char* w2 = (char*)bufC;
  auto take2 = [&](size_t bytes) -> char* {
    char* p = w2;
    w2 += (bytes + 255) & ~(size_t)255;
    return p;
  };
  float*    psum = (float*)take2((size_t)N_GRAPH * HID * sizeof(float));
  unsigned* pmax = (unsigned*)take2((size_t)N_GRAPH * HID * sizeof(unsigned));
  int*      pcnt = (int*)take2(N_GRAPH * sizeof(int));
  float*    ge   = (float*)take2((size_t)N_GRAPH * 512 * sizeof(float));
  float*    tbuf = (float*)take2((size_t)N_GRAPH * 512 * sizeof(float));

  const int EB = (N_EDGES + 255) / 256;
  const int WB = (N_NODES + 3) / 4;     // wave-per-row blocks

  // --- CSR (dst-sorted) ---
  hipMemsetAsync(counts, 0, N_NODES * sizeof(int), stream);
  edge_count<<<EB, 256, 0, stream>>>(ei, counts);
  scan_counts<<<1, 1024, 0, stream>>>(counts, indptr, cursor, N_NODES);
  edge_scatter<<<EB, 256, 0, stream>>>(ei, cursor, esrc);

  // --- input embed: h = gelu(LN(x @ in_W + in_b)) ---
  gemm_launch(x, in_W, in_b, bufA, N_NODES, HID, F_INPUT, 0, stream);
  ln_act<<<WB, 256, 0, stream>>>(bufA, nullptr, nullptr, in_ln_g, in_ln_b, h,
                                 N_NODES, HID, 1);

  // --- 5 GATv2 layers ---
  for (int l = 0; l < NLAYER; ++l) {
    const float* Wl = gat_Wl + (size_t)l * HID * HID;
    const float* Wr = gat_Wr + (size_t)l * HID * HID;
    gemm_launch(h, Wl, gat_bl + l * HID, bufA, N_NODES, HID, HID, 0, stream);
    gemm_launch(h, Wr, gat_br + l * HID, bufB, N_NODES, HID, HID, 0, stream);
    // out aliases xr (bufB) -- safe per kernel comment
    gat_agg<<<WB, 256, 0, stream>>>(bufA, bufB, gat_att + l * HID, indptr, esrc, bufB);
    ln_act<<<WB, 256, 0, stream>>>(bufB, gat_bias + l * HID, h,
                                   gat_ln_g + l * HID, gat_ln_b + l * HID, h,
                                   N_NODES, HID, 1);
  }

  // --- TransformerConv ---
  gemm_launch(h, tr_Wq, tr_bq, bufA, N_NODES, HID, HID, 0, stream);  // q
  gemm_launch(h, tr_Wk, tr_bk, bufB, N_NODES, HID, HID, 0, stream);  // k
  gemm_launch(h, tr_Wv, tr_bv, bufC, N_NODES, HID, HID, 0, stream);  // v
  // out aliases q (bufA) -- safe per kernel comment
  tr_agg<<<WB, 256, 0, stream>>>(bufA, bufB, bufC, indptr, esrc, bufA);
  gemm_launch(h, tr_Wsk, tr_bsk, bufA, N_NODES, HID, HID, 1, stream);  // += skip
  ln_act<<<WB, 256, 0, stream>>>(bufA, nullptr, h, tr_ln_g, tr_ln_b, h,
                                 N_NODES, HID, 0);

  // --- global mean+max pool -> ge[G,512] (scratch overlays bufC, now free) ---
  hipMemsetAsync(psum, 0, (size_t)N_GRAPH * HID * sizeof(float), stream);
  hipMemsetAsync(pcnt, 0, N_GRAPH * sizeof(int), stream);
  fill_u32<<<(N_GRAPH * HID + 255) / 256, 256, 0, stream>>>(pmax, MAXKEY_INIT, N_GRAPH * HID);
  pool_scatter<<<(N_NODES * 64 + 255) / 256, 256, 0, stream>>>(h, batch, psum, pmax, pcnt);
  pool_finalize<<<(N_GRAPH * HID + 255) / 256, 256, 0, stream>>>(psum, pmax, pcnt, ge);

  // --- output proj: out = gelu(LN(ge @ out_W + out_b)) ---
  gemm_launch(ge, out_W, out_b, tbuf, N_GRAPH, 512, 512, 0, stream);
  ln_act<<<(N_GRAPH + 3) / 4, 256, 0, stream>>>(tbuf, nullptr, nullptr,
                                                out_ln_g, out_ln_b, (float*)d_out,
                                                N_GRAPH, 512, 1);
}

// Round 3
// 2103.179 us; speedup vs baseline: 1.7690x; 1.7690x over previous
//
#include <hip/hip_runtime.h>
#include <math.h>

#define N_NODES 50000
#define N_EDGES 800000
#define N_GRAPH 2000
#define F_INPUT 34
#define HID 256
#define NLAYER 5

typedef __attribute__((ext_vector_type(8))) short short8;
typedef __attribute__((ext_vector_type(4))) float float4v;

// ---------- helpers ----------
__device__ __forceinline__ float gelu_f(float x) {
  return 0.5f * x * (1.0f + erff(x * 0.70710678118654752440f));
}
__device__ __forceinline__ unsigned short bfr(float f) {  // fp32 -> bf16 RNE
  unsigned u = __float_as_uint(f);
  return (unsigned short)((u + 0x7fffu + ((u >> 16) & 1u)) >> 16);
}

// ---------- fp32 GEMM (small shapes: input embed K=34, out proj) ----------
__global__ __launch_bounds__(256) void gemm_bias(
    const float* __restrict__ A, const float* __restrict__ B,
    const float* __restrict__ bias, float* __restrict__ C,
    int M, int Nn, int K, int accum) {
  __shared__ float As[16][64];
  __shared__ float Bs[16][64];
  int tid = threadIdx.x;
  int tx = tid & 15, ty = tid >> 4;
  int row0 = blockIdx.y * 64;
  int col0 = blockIdx.x * 64;
  float acc[4][4] = {};
  int a_r = tid >> 2;
  int a_c = (tid & 3) * 4;
  int b_r = tid >> 4;
  int b_c = (tid & 15) * 4;

  for (int k0 = 0; k0 < K; k0 += 16) {
    int ar = row0 + a_r;
#pragma unroll
    for (int i = 0; i < 4; ++i) {
      int kc = k0 + a_c + i;
      As[a_c + i][a_r] = (ar < M && kc < K) ? A[(long)ar * K + kc] : 0.f;
    }
    int bk = k0 + b_r;
    if (bk < K) {
      float4 bv = *(const float4*)&B[(long)bk * Nn + col0 + b_c];
      Bs[b_r][b_c + 0] = bv.x; Bs[b_r][b_c + 1] = bv.y;
      Bs[b_r][b_c + 2] = bv.z; Bs[b_r][b_c + 3] = bv.w;
    } else {
      Bs[b_r][b_c + 0] = 0.f; Bs[b_r][b_c + 1] = 0.f;
      Bs[b_r][b_c + 2] = 0.f; Bs[b_r][b_c + 3] = 0.f;
    }
    __syncthreads();
#pragma unroll
    for (int kk = 0; kk < 16; ++kk) {
      float4 a = *(const float4*)&As[kk][ty * 4];
      float4 b = *(const float4*)&Bs[kk][tx * 4];
      float av[4] = {a.x, a.y, a.z, a.w};
      float bv[4] = {b.x, b.y, b.z, b.w};
#pragma unroll
      for (int i = 0; i < 4; ++i)
#pragma unroll
        for (int j = 0; j < 4; ++j) acc[i][j] += av[i] * bv[j];
    }
    __syncthreads();
  }
  float4 bi = *(const float4*)&bias[col0 + tx * 4];
  float bia[4] = {bi.x, bi.y, bi.z, bi.w};
#pragma unroll
  for (int i = 0; i < 4; ++i) {
    int r = row0 + ty * 4 + i;
    if (r < M) {
      float4* cp = (float4*)&C[(long)r * Nn + col0 + tx * 4];
      float4 o;
      o.x = acc[i][0] + bia[0]; o.y = acc[i][1] + bia[1];
      o.z = acc[i][2] + bia[2]; o.w = acc[i][3] + bia[3];
      if (accum) {
        float4 old = *cp;
        o.x += old.x; o.y += old.y; o.z += old.z; o.w += old.w;
      }
      *cp = o;
    }
  }
}

// ---------- bf16 MFMA GEMM: C[M,Nn] = A@B + bias (+C) ----------
// A: [M][K] bf16 ; Bt: [Nn][K] bf16 (transposed weights) ; C fp32.
// 128x128 block tile, 4 waves in 2x2, each wave 64x64 via 4x4 16x16x32 frags.
__global__ __launch_bounds__(256) void gemm_mfma(
    const unsigned short* __restrict__ A, const unsigned short* __restrict__ Bt,
    const float* __restrict__ bias, float* __restrict__ C,
    int M, int Nn, int K, int accum) {
  __shared__ unsigned short As[128][40];  // +8 pad: 2-way bank alias only
  __shared__ unsigned short Bs[128][40];
  int tid = threadIdx.x;
  int wave = tid >> 6, lane = tid & 63;
  int row0 = blockIdx.y * 128;
  int col0 = blockIdx.x * 128;
  int wm0 = (wave >> 1) * 64;
  int wn0 = (wave & 1) * 64;
  int lr = tid >> 2;          // staging row 0..63
  int lc = (tid & 3) * 8;     // staging k-offset (elems)
  int q = lane >> 4;          // quad
  int ln = lane & 15;

  float4v acc[4][4];
#pragma unroll
  for (int i = 0; i < 4; ++i)
#pragma unroll
    for (int j = 0; j < 4; ++j) acc[i][j] = (float4v)0.f;

  for (int k0 = 0; k0 < K; k0 += 32) {
    int r1 = row0 + lr, r2 = row0 + lr + 64;
    uint4 za = {0u, 0u, 0u, 0u};
    uint4 va = (r1 < M) ? *(const uint4*)&A[(size_t)r1 * K + k0 + lc] : za;
    uint4 vb = (r2 < M) ? *(const uint4*)&A[(size_t)r2 * K + k0 + lc] : za;
    uint4 wa = *(const uint4*)&Bt[(size_t)(col0 + lr) * K + k0 + lc];
    uint4 wb = *(const uint4*)&Bt[(size_t)(col0 + lr + 64) * K + k0 + lc];
    *(uint4*)&As[lr][lc] = va;
    *(uint4*)&As[lr + 64][lc] = vb;
    *(uint4*)&Bs[lr][lc] = wa;
    *(uint4*)&Bs[lr + 64][lc] = wb;
    __syncthreads();
    short8 af[4], bf[4];
#pragma unroll
    for (int i = 0; i < 4; ++i) af[i] = *(const short8*)&As[wm0 + i * 16 + ln][q * 8];
#pragma unroll
    for (int j = 0; j < 4; ++j) bf[j] = *(const short8*)&Bs[wn0 + j * 16 + ln][q * 8];
#pragma unroll
    for (int i = 0; i < 4; ++i)
#pragma unroll
      for (int j = 0; j < 4; ++j)
        acc[i][j] = __builtin_amdgcn_mfma_f32_16x16x32_bf16(af[i], bf[j], acc[i][j], 0, 0, 0);
    __syncthreads();
  }
  int rb = (lane >> 4) * 4;   // C row base: (lane>>4)*4 + reg
#pragma unroll
  for (int j = 0; j < 4; ++j) {
    int col = col0 + wn0 + j * 16 + ln;
    float bv = bias[col];
#pragma unroll
    for (int i = 0; i < 4; ++i) {
#pragma unroll
      for (int r = 0; r < 4; ++r) {
        int row = row0 + wm0 + i * 16 + rb + r;
        if (row < M) {
          float v = acc[i][j][r] + bv;
          if (accum) v += C[(size_t)row * Nn + col];
          C[(size_t)row * Nn + col] = v;
        }
      }
    }
  }
}

// ---------- weight prep: Wt_bf16[n][k] = bf16(W[k][n]), 14 mats of 256x256 ----------
__global__ __launch_bounds__(256) void prep_w(
    const float* __restrict__ Wl, const float* __restrict__ Wr,
    const float* __restrict__ Wq, const float* __restrict__ Wk,
    const float* __restrict__ Wv, const float* __restrict__ Wsk,
    unsigned short* __restrict__ out) {
  __shared__ float t[32][33];
  int m = blockIdx.z;
  const float* W = (m < 5)  ? Wl + (size_t)m * 65536
                 : (m < 10) ? Wr + (size_t)(m - 5) * 65536
                 : (m == 10) ? Wq : (m == 11) ? Wk : (m == 12) ? Wv : Wsk;
  int k0 = blockIdx.y * 32, n0 = blockIdx.x * 32;
  int r = threadIdx.x >> 5, c = threadIdx.x & 31;
  for (int rr = r; rr < 32; rr += 8)
    t[rr][c] = W[(size_t)(k0 + rr) * HID + n0 + c];
  __syncthreads();
  unsigned short* o = out + (size_t)m * 65536;
  for (int rr = r; rr < 32; rr += 8)
    o[(size_t)(n0 + rr) * HID + k0 + c] = bfr(t[c][rr]);
}

// ---------- LayerNorm (+pre-bias)(+GELU)(+residual)(+bf16 copy) ----------
__global__ __launch_bounds__(256) void ln_act(
    const float* __restrict__ in, const float* __restrict__ pre_bias,
    const float* __restrict__ res, const float* __restrict__ gam,
    const float* __restrict__ bet, float* __restrict__ out,
    unsigned short* __restrict__ outb,
    int n_rows, int width, int do_gelu) {
  int wid = blockIdx.x * 4 + (threadIdx.x >> 6);
  int lane = threadIdx.x & 63;
  if (wid >= n_rows) return;
  int chunks = width >> 8;
  float4 v[2];
  float s = 0.f;
  for (int c = 0; c < chunks; ++c) {
    int off = c * 256 + lane * 4;
    float4 t = *(const float4*)&in[(size_t)wid * width + off];
    if (pre_bias) {
      float4 pb = *(const float4*)&pre_bias[off];
      t.x += pb.x; t.y += pb.y; t.z += pb.z; t.w += pb.w;
    }
    v[c] = t;
    s += t.x + t.y + t.z + t.w;
  }
  for (int o = 1; o < 64; o <<= 1) s += __shfl_xor(s, o);
  float mean = s / (float)width;
  float vs = 0.f;
  for (int c = 0; c < chunks; ++c) {
    float dx = v[c].x - mean, dy = v[c].y - mean, dz = v[c].z - mean, dw = v[c].w - mean;
    vs += dx * dx + dy * dy + dz * dz + dw * dw;
  }
  for (int o = 1; o < 64; o <<= 1) vs += __shfl_xor(vs, o);
  float inv = rsqrtf(vs / (float)width + 1e-5f);
  for (int c = 0; c < chunks; ++c) {
    int off = c * 256 + lane * 4;
    float4 g4 = *(const float4*)&gam[off];
    float4 b4 = *(const float4*)&bet[off];
    float y[4] = {(v[c].x - mean) * inv * g4.x + b4.x,
                  (v[c].y - mean) * inv * g4.y + b4.y,
                  (v[c].z - mean) * inv * g4.z + b4.z,
                  (v[c].w - mean) * inv * g4.w + b4.w};
    if (do_gelu) {
#pragma unroll
      for (int i = 0; i < 4; ++i) y[i] = gelu_f(y[i]);
    }
    size_t idx = (size_t)wid * width + off;
    if (res) {
      float4 r4 = *(const float4*)&res[idx];
      y[0] += r4.x; y[1] += r4.y; y[2] += r4.z; y[3] += r4.w;
    }
    float4 o4 = {y[0], y[1], y[2], y[3]};
    *(float4*)&out[idx] = o4;
    if (outb) {
      ushort4 ob = {bfr(y[0]), bfr(y[1]), bfr(y[2]), bfr(y[3])};
      *(ushort4*)&outb[idx] = ob;
    }
  }
}

// ---------- CSR build ----------
__global__ __launch_bounds__(256) void edge_count(const int* __restrict__ ei,
                                                  int* __restrict__ counts) {
  int e = blockIdx.x * 256 + threadIdx.x;
  if (e < N_EDGES) atomicAdd(&counts[ei[N_EDGES + e]], 1);
}

__global__ __launch_bounds__(1024) void scan_counts(const int* __restrict__ counts,
                                                    int* __restrict__ indptr,
                                                    int* __restrict__ cursor, int n) {
  __shared__ int sm[1024];
  __shared__ int carry;
  int tid = threadIdx.x;
  if (tid == 0) carry = 0;
  __syncthreads();
  for (int base = 0; base < n; base += 1024) {
    int i = base + tid;
    int v = (i < n) ? counts[i] : 0;
    sm[tid] = v;
    __syncthreads();
    for (int off = 1; off < 1024; off <<= 1) {
      int t = (tid >= off) ? sm[tid - off] : 0;
      __syncthreads();
      sm[tid] += t;
      __syncthreads();
    }
    int excl = sm[tid] - v + carry;
    if (i < n) { indptr[i] = excl; cursor[i] = excl; }
    int total = sm[1023];
    __syncthreads();
    if (tid == 0) carry += total;
    __syncthreads();
  }
  if (tid == 0) indptr[n] = carry;
}

__global__ __launch_bounds__(256) void edge_scatter(const int* __restrict__ ei,
                                                    int* __restrict__ cursor,
                                                    int* __restrict__ esrc) {
  int e = blockIdx.x * 256 + threadIdx.x;
  if (e < N_EDGES) {
    int d = ei[N_EDGES + e];
    int p = atomicAdd(&cursor[d], 1);
    esrc[p] = ei[e];
  }
}

// ---------- GATv2 aggregation (wave per dst node, online softmax) ----------
__global__ __launch_bounds__(256) void gat_agg(
    const float* __restrict__ xl, const float* __restrict__ xr,
    const float* __restrict__ att, const int* __restrict__ indptr,
    const int* __restrict__ esrc, float* __restrict__ out) {
  int wid = blockIdx.x * 4 + (threadIdx.x >> 6);
  int lane = threadIdx.x & 63;
  if (wid >= N_NODES) return;
  float4 xri = *(const float4*)&xr[(size_t)wid * HID + lane * 4];
  float4 a4 = *(const float4*)&att[lane * 4];
  int beg = indptr[wid], end = indptr[wid + 1];
  float m = -INFINITY, lsum = 0.f;
  float ax = 0.f, ay = 0.f, az = 0.f, aw = 0.f;
  for (int e = beg - 1; e < end; ++e) {
    int j = (e < beg) ? wid : esrc[e];
    float4 xlj = *(const float4*)&xl[(size_t)j * HID + lane * 4];
    float ex = xlj.x + xri.x; ex = ex > 0.f ? ex : 0.2f * ex;
    float ey = xlj.y + xri.y; ey = ey > 0.f ? ey : 0.2f * ey;
    float ez = xlj.z + xri.z; ez = ez > 0.f ? ez : 0.2f * ez;
    float ew = xlj.w + xri.w; ew = ew > 0.f ? ew : 0.2f * ew;
    float p = ex * a4.x + ey * a4.y + ez * a4.z + ew * a4.w;
    p += __shfl_xor(p, 1); p += __shfl_xor(p, 2); p += __shfl_xor(p, 4);
    float sc = p;
    if (sc > m) {
      float f = __expf(m - sc);
      ax *= f; ay *= f; az *= f; aw *= f; lsum *= f;
      m = sc;
    }
    float w = __expf(sc - m);
    ax += w * xlj.x; ay += w * xlj.y; az += w * xlj.z; aw += w * xlj.w;
    lsum += w;
  }
  float inv = 1.f / (lsum + 1e-16f);
  float4 o = {ax * inv, ay * inv, az * inv, aw * inv};
  *(float4*)&out[(size_t)wid * HID + lane * 4] = o;
}

// ---------- TransformerConv aggregation ----------
__global__ __launch_bounds__(256) void tr_agg(
    const float* __restrict__ q, const float* __restrict__ k,
    const float* __restrict__ v, const int* __restrict__ indptr,
    const int* __restrict__ esrc, float* __restrict__ out) {
  int wid = blockIdx.x * 4 + (threadIdx.x >> 6);
  int lane = threadIdx.x & 63;
  if (wid >= N_NODES) return;
  float4 qi = *(const float4*)&q[(size_t)wid * HID + lane * 4];
  int beg = indptr[wid], end = indptr[wid + 1];
  float m = -INFINITY, lsum = 0.f;
  float ax = 0.f, ay = 0.f, az = 0.f, aw = 0.f;
  const float scale = 0.17677669529663687f;
  for (int e = beg; e < end; ++e) {
    int j = esrc[e];
    float4 kj = *(const float4*)&k[(size_t)j * HID + lane * 4];
    float p = qi.x * kj.x + qi.y * kj.y + qi.z * kj.z + qi.w * kj.w;
    p += __shfl_xor(p, 1); p += __shfl_xor(p, 2); p += __shfl_xor(p, 4);
    float sc = p * scale;
    float4 vj = *(const float4*)&v[(size_t)j * HID + lane * 4];
    if (sc > m) {
      float f = __expf(m - sc);
      ax *= f; ay *= f; az *= f; aw *= f; lsum *= f;
      m = sc;
    }
    float w = __expf(sc - m);
    ax += w * vj.x; ay += w * vj.y; az += w * vj.z; aw += w * vj.w;
    lsum += w;
  }
  float inv = 1.f / (lsum + 1e-16f);
  float4 o = {ax * inv, ay * inv, az * inv, aw * inv};
  *(float4*)&out[(size_t)wid * HID + lane * 4] = o;
}

// ---------- pooling over sorted batch ----------
__global__ __launch_bounds__(256) void graph_bounds(const int* __restrict__ batch,
                                                    int* __restrict__ gptr) {
  int i = blockIdx.x * 256 + threadIdx.x;
  if (i >= N_NODES) return;
  int b0 = batch[i];
  if (i == 0)
    for (int g = 0; g <= b0; ++g) gptr[g] = 0;
  int b1 = (i + 1 < N_NODES) ? batch[i + 1] : N_GRAPH;
  for (int g = b0 + 1; g <= b1; ++g) gptr[g] = i + 1;
}

__global__ __launch_bounds__(256) void pool_seg(
    const float* __restrict__ h, const int* __restrict__ gptr,
    float* __restrict__ ge) {
  int g = blockIdx.x, c = threadIdx.x;
  int s = gptr[g], e = gptr[g + 1];
  float sum = 0.f, mx = -INFINITY;
  for (int r = s; r < e; ++r) {
    float vv = h[(size_t)r * HID + c];
    sum += vv;
    mx = fmaxf(mx, vv);
  }
  int cnt = e - s;
  ge[(size_t)g * 512 + c] = sum / (float)max(cnt, 1);
  ge[(size_t)g * 512 + 256 + c] = cnt ? mx : 0.f;
}

// ---------- host launch ----------
static inline void gemm_launch(const float* A, const float* B, const float* bias,
                               float* C, int M, int Nn, int K, int accum,
                               hipStream_t s) {
  dim3 grid(Nn / 64, (M + 63) / 64);
  gemm_bias<<<grid, 256, 0, s>>>(A, B, bias, C, M, Nn, K, accum);
}
static inline void mfma_launch(const unsigned short* A, const unsigned short* Bt,
                               const float* bias, float* C, int M, int Nn, int K,
                               int accum, hipStream_t s) {
  dim3 grid(Nn / 128, (M + 127) / 128);
  gemm_mfma<<<grid, 256, 0, s>>>(A, Bt, bias, C, M, Nn, K, accum);
}

extern "C" void kernel_launch(void* const* d_in, const int* in_sizes, int n_in,
                              void* d_out, int out_size, void* d_ws, size_t ws_size,
                              hipStream_t stream) {
  const float* x       = (const float*)d_in[0];
  const int*   ei      = (const int*)d_in[1];
  const int*   batch   = (const int*)d_in[2];
  const float* in_W    = (const float*)d_in[3];
  const float* in_b    = (const float*)d_in[4];
  const float* in_ln_g = (const float*)d_in[5];
  const float* in_ln_b = (const float*)d_in[6];
  const float* gat_Wl  = (const float*)d_in[7];
  const float* gat_bl  = (const float*)d_in[8];
  const float* gat_Wr  = (const float*)d_in[9];
  const float* gat_br  = (const float*)d_in[10];
  const float* gat_att = (const float*)d_in[11];
  const float* gat_bias= (const float*)d_in[12];
  const float* gat_ln_g= (const float*)d_in[13];
  const float* gat_ln_b= (const float*)d_in[14];
  const float* tr_Wq   = (const float*)d_in[15];
  const float* tr_bq   = (const float*)d_in[16];
  const float* tr_Wk   = (const float*)d_in[17];
  const float* tr_bk   = (const float*)d_in[18];
  const float* tr_Wv   = (const float*)d_in[19];
  const float* tr_bv   = (const float*)d_in[20];
  const float* tr_Wsk  = (const float*)d_in[21];
  const float* tr_bsk  = (const float*)d_in[22];
  const float* tr_ln_g = (const float*)d_in[23];
  const float* tr_ln_b = (const float*)d_in[24];
  const float* out_W   = (const float*)d_in[25];
  const float* out_b   = (const float*)d_in[26];
  const float* out_ln_g= (const float*)d_in[27];
  const float* out_ln_b= (const float*)d_in[28];

  // ---- workspace (256B-aligned slices) ----
  char* w = (char*)d_ws;
  auto take = [&](size_t bytes) -> char* {
    char* p = w;
    w += (bytes + 255) & ~(size_t)255;
    return p;
  };
  const size_t NB = (size_t)N_NODES * HID * sizeof(float);     // 51.2 MB
  float* h    = (float*)take(NB);
  float* bufA = (float*)take(NB);
  float* bufB = (float*)take(NB);
  float* bufC = (float*)take(NB);
  unsigned short* hb   = (unsigned short*)take((size_t)N_NODES * HID * 2);  // 25.6 MB
  unsigned short* wbuf = (unsigned short*)take((size_t)14 * HID * HID * 2); // 1.8 MB
  int* indptr = (int*)take((N_NODES + 1) * sizeof(int));
  int* cursor = (int*)take(N_NODES * sizeof(int));
  int* counts = (int*)take(N_NODES * sizeof(int));
  int* esrc   = (int*)take(N_EDGES * sizeof(int));
  // pool/output scratch overlays bufC (free after tr_agg)
  char* w2 = (char*)bufC;
  auto take2 = [&](size_t bytes) -> char* {
    char* p = w2;
    w2 += (bytes + 255) & ~(size_t)255;
    return p;
  };
  int*   gptr = (int*)take2((N_GRAPH + 1) * sizeof(int));
  float* ge   = (float*)take2((size_t)N_GRAPH * 512 * sizeof(float));
  float* tbuf = (float*)take2((size_t)N_GRAPH * 512 * sizeof(float));

  const int EB = (N_EDGES + 255) / 256;
  const int WB = (N_NODES + 3) / 4;

  // --- weight prep (bf16 transpose) ---
  {
    dim3 g(8, 8, 14);
    prep_w<<<g, 256, 0, stream>>>(gat_Wl, gat_Wr, tr_Wq, tr_Wk, tr_Wv, tr_Wsk, wbuf);
  }

  // --- CSR (dst-sorted) ---
  hipMemsetAsync(counts, 0, N_NODES * sizeof(int), stream);
  edge_count<<<EB, 256, 0, stream>>>(ei, counts);
  scan_counts<<<1, 1024, 0, stream>>>(counts, indptr, cursor, N_NODES);
  edge_scatter<<<EB, 256, 0, stream>>>(ei, cursor, esrc);

  // --- input embed: h = gelu(LN(x @ in_W + in_b)) ; also hb=bf16(h) ---
  gemm_launch(x, in_W, in_b, bufA, N_NODES, HID, F_INPUT, 0, stream);
  ln_act<<<WB, 256, 0, stream>>>(bufA, nullptr, nullptr, in_ln_g, in_ln_b, h, hb,
                                 N_NODES, HID, 1);

  // --- 5 GATv2 layers ---
  for (int l = 0; l < NLAYER; ++l) {
    const unsigned short* Wl = wbuf + (size_t)l * 65536;
    const unsigned short* Wr = wbuf + (size_t)(5 + l) * 65536;
    mfma_launch(hb, Wl, gat_bl + l * HID, bufA, N_NODES, HID, HID, 0, stream);
    mfma_launch(hb, Wr, gat_br + l * HID, bufB, N_NODES, HID, HID, 0, stream);
    gat_agg<<<WB, 256, 0, stream>>>(bufA, bufB, gat_att + l * HID, indptr, esrc, bufB);
    ln_act<<<WB, 256, 0, stream>>>(bufB, gat_bias + l * HID, h,
                                   gat_ln_g + l * HID, gat_ln_b + l * HID, h, hb,
                                   N_NODES, HID, 1);
  }

  // --- TransformerConv ---
  mfma_launch(hb, wbuf + (size_t)10 * 65536, tr_bq, bufA, N_NODES, HID, HID, 0, stream);
  mfma_launch(hb, wbuf + (size_t)11 * 65536, tr_bk, bufB, N_NODES, HID, HID, 0, stream);
  mfma_launch(hb, wbuf + (size_t)12 * 65536, tr_bv, bufC, N_NODES, HID, HID, 0, stream);
  tr_agg<<<WB, 256, 0, stream>>>(bufA, bufB, bufC, indptr, esrc, bufA);
  mfma_launch(hb, wbuf + (size_t)13 * 65536, tr_bsk, bufA, N_NODES, HID, HID, 1, stream);
  ln_act<<<WB, 256, 0, stream>>>(bufA, nullptr, h, tr_ln_g, tr_ln_b, h, nullptr,
                                 N_NODES, HID, 0);

  // --- pooling (batch sorted -> contiguous segments; overlay bufC now free) ---
  graph_bounds<<<(N_NODES + 255) / 256, 256, 0, stream>>>(batch, gptr);
  pool_seg<<<N_GRAPH, 256, 0, stream>>>(h, gptr, ge);

  // --- output proj: out = gelu(LN(ge @ out_W + out_b)) ---
  gemm_launch(ge, out_W, out_b, tbuf, N_GRAPH, 512, 512, 0, stream);
  ln_act<<<(N_GRAPH + 3) / 4, 256, 0, stream>>>(tbuf, nullptr, nullptr,
                                                out_ln_g, out_ln_b, (float*)d_out,
                                                nullptr, N_GRAPH, 512, 1);
}

// Round 4
// 1887.669 us; speedup vs baseline: 1.9710x; 1.1142x over previous
//
#include <hip/hip_runtime.h>
#include <math.h>

#define N_NODES 50000
#define N_EDGES 800000
#define N_GRAPH 2000
#define F_INPUT 34
#define HID 256
#define NLAYER 5

typedef __attribute__((ext_vector_type(8))) short short8;
typedef __attribute__((ext_vector_type(4))) float float4v;

// ---------- helpers ----------
__device__ __forceinline__ float gelu_f(float x) {
  return 0.5f * x * (1.0f + erff(x * 0.70710678118654752440f));
}
__device__ __forceinline__ unsigned short bfr(float f) {  // fp32 -> bf16 RNE
  unsigned u = __float_as_uint(f);
  return (unsigned short)((u + 0x7fffu + ((u >> 16) & 1u)) >> 16);
}
__device__ __forceinline__ float b2f(unsigned short s) {
  return __uint_as_float(((unsigned)s) << 16);
}
__device__ __forceinline__ float4 ld4bf(const unsigned short* p) {
  ushort4 u = *(const ushort4*)p;
  float4 f;
  f.x = b2f(u.x); f.y = b2f(u.y); f.z = b2f(u.z); f.w = b2f(u.w);
  return f;
}

// ---------- fp32 GEMM (input embed K=34, out proj 512x512) ----------
__global__ __launch_bounds__(256) void gemm_bias(
    const float* __restrict__ A, const float* __restrict__ B,
    const float* __restrict__ bias, float* __restrict__ C,
    int M, int Nn, int K, int accum) {
  __shared__ float As[16][64];
  __shared__ float Bs[16][64];
  int tid = threadIdx.x;
  int tx = tid & 15, ty = tid >> 4;
  int row0 = blockIdx.y * 64;
  int col0 = blockIdx.x * 64;
  float acc[4][4] = {};
  int a_r = tid >> 2;
  int a_c = (tid & 3) * 4;
  int b_r = tid >> 4;
  int b_c = (tid & 15) * 4;

  for (int k0 = 0; k0 < K; k0 += 16) {
    int ar = row0 + a_r;
#pragma unroll
    for (int i = 0; i < 4; ++i) {
      int kc = k0 + a_c + i;
      As[a_c + i][a_r] = (ar < M && kc < K) ? A[(long)ar * K + kc] : 0.f;
    }
    int bk = k0 + b_r;
    if (bk < K) {
      float4 bv = *(const float4*)&B[(long)bk * Nn + col0 + b_c];
      Bs[b_r][b_c + 0] = bv.x; Bs[b_r][b_c + 1] = bv.y;
      Bs[b_r][b_c + 2] = bv.z; Bs[b_r][b_c + 3] = bv.w;
    } else {
      Bs[b_r][b_c + 0] = 0.f; Bs[b_r][b_c + 1] = 0.f;
      Bs[b_r][b_c + 2] = 0.f; Bs[b_r][b_c + 3] = 0.f;
    }
    __syncthreads();
#pragma unroll
    for (int kk = 0; kk < 16; ++kk) {
      float4 a = *(const float4*)&As[kk][ty * 4];
      float4 b = *(const float4*)&Bs[kk][tx * 4];
      float av[4] = {a.x, a.y, a.z, a.w};
      float bv[4] = {b.x, b.y, b.z, b.w};
#pragma unroll
      for (int i = 0; i < 4; ++i)
#pragma unroll
        for (int j = 0; j < 4; ++j) acc[i][j] += av[i] * bv[j];
    }
    __syncthreads();
  }
  float4 bi = *(const float4*)&bias[col0 + tx * 4];
  float bia[4] = {bi.x, bi.y, bi.z, bi.w};
#pragma unroll
  for (int i = 0; i < 4; ++i) {
    int r = row0 + ty * 4 + i;
    if (r < M) {
      float4* cp = (float4*)&C[(long)r * Nn + col0 + tx * 4];
      float4 o;
      o.x = acc[i][0] + bia[0]; o.y = acc[i][1] + bia[1];
      o.z = acc[i][2] + bia[2]; o.w = acc[i][3] + bia[3];
      if (accum) {
        float4 old = *cp;
        o.x += old.x; o.y += old.y; o.z += old.z; o.w += old.w;
      }
      *cp = o;
    }
  }
}

// ---------- bf16 MFMA GEMM ----------
// A: [M][K] bf16 ; Bt: [Nn][K] bf16 ; bias fp32.
// flags: bit0 = accumulate into fp32 C ; bit1 = write bf16 output.
// 128x128 block tile, 4 waves 2x2, each wave 64x64 via 4x4 16x16x32 frags.
__global__ __launch_bounds__(256) void gemm_mfma(
    const unsigned short* __restrict__ A, const unsigned short* __restrict__ Bt,
    const float* __restrict__ bias, void* __restrict__ Cv,
    int M, int Nn, int K, int flags) {
  __shared__ unsigned short As[128][40];
  __shared__ unsigned short Bs[128][40];
  int tid = threadIdx.x;
  int wave = tid >> 6, lane = tid & 63;
  int row0 = blockIdx.y * 128;
  int col0 = blockIdx.x * 128;
  int wm0 = (wave >> 1) * 64;
  int wn0 = (wave & 1) * 64;
  int lr = tid >> 2;
  int lc = (tid & 3) * 8;
  int q = lane >> 4;
  int ln = lane & 15;

  float4v acc[4][4];
#pragma unroll
  for (int i = 0; i < 4; ++i)
#pragma unroll
    for (int j = 0; j < 4; ++j) acc[i][j] = (float4v)0.f;

  for (int k0 = 0; k0 < K; k0 += 32) {
    int r1 = row0 + lr, r2 = row0 + lr + 64;
    uint4 za = {0u, 0u, 0u, 0u};
    uint4 va = (r1 < M) ? *(const uint4*)&A[(size_t)r1 * K + k0 + lc] : za;
    uint4 vb = (r2 < M) ? *(const uint4*)&A[(size_t)r2 * K + k0 + lc] : za;
    uint4 wa = *(const uint4*)&Bt[(size_t)(col0 + lr) * K + k0 + lc];
    uint4 wb = *(const uint4*)&Bt[(size_t)(col0 + lr + 64) * K + k0 + lc];
    *(uint4*)&As[lr][lc] = va;
    *(uint4*)&As[lr + 64][lc] = vb;
    *(uint4*)&Bs[lr][lc] = wa;
    *(uint4*)&Bs[lr + 64][lc] = wb;
    __syncthreads();
    short8 af[4], bf[4];
#pragma unroll
    for (int i = 0; i < 4; ++i) af[i] = *(const short8*)&As[wm0 + i * 16 + ln][q * 8];
#pragma unroll
    for (int j = 0; j < 4; ++j) bf[j] = *(const short8*)&Bs[wn0 + j * 16 + ln][q * 8];
#pragma unroll
    for (int i = 0; i < 4; ++i)
#pragma unroll
      for (int j = 0; j < 4; ++j)
        acc[i][j] = __builtin_amdgcn_mfma_f32_16x16x32_bf16(af[i], bf[j], acc[i][j], 0, 0, 0);
    __syncthreads();
  }
  int rb = (lane >> 4) * 4;
  if (flags & 2) {
    unsigned short* Cb = (unsigned short*)Cv;
#pragma unroll
    for (int j = 0; j < 4; ++j) {
      int col = col0 + wn0 + j * 16 + ln;
      float bv = bias[col];
#pragma unroll
      for (int i = 0; i < 4; ++i)
#pragma unroll
        for (int r = 0; r < 4; ++r) {
          int row = row0 + wm0 + i * 16 + rb + r;
          if (row < M) Cb[(size_t)row * Nn + col] = bfr(acc[i][j][r] + bv);
        }
    }
  } else {
    float* C = (float*)Cv;
#pragma unroll
    for (int j = 0; j < 4; ++j) {
      int col = col0 + wn0 + j * 16 + ln;
      float bv = bias[col];
#pragma unroll
      for (int i = 0; i < 4; ++i)
#pragma unroll
        for (int r = 0; r < 4; ++r) {
          int row = row0 + wm0 + i * 16 + rb + r;
          if (row < M) {
            float v = acc[i][j][r] + bv;
            if (flags & 1) v += C[(size_t)row * Nn + col];
            C[(size_t)row * Nn + col] = v;
          }
        }
    }
  }
}

// ---------- weight prep: Wt_bf16[n][k] = bf16(W[k][n]) ----------
// slots: 2l=Wl_l, 2l+1=Wr_l (l<5); 10=q, 11=k, 12=v, 13=skip
__global__ __launch_bounds__(256) void prep_w(
    const float* __restrict__ Wl, const float* __restrict__ Wr,
    const float* __restrict__ Wq, const float* __restrict__ Wk,
    const float* __restrict__ Wv, const float* __restrict__ Wsk,
    unsigned short* __restrict__ out) {
  __shared__ float t[32][33];
  int m = blockIdx.z;
  const float* W = (m < 10) ? (((m & 1) ? Wr : Wl) + (size_t)(m >> 1) * 65536)
                 : (m == 10) ? Wq : (m == 11) ? Wk : (m == 12) ? Wv : Wsk;
  int k0 = blockIdx.y * 32, n0 = blockIdx.x * 32;
  int r = threadIdx.x >> 5, c = threadIdx.x & 31;
  for (int rr = r; rr < 32; rr += 8)
    t[rr][c] = W[(size_t)(k0 + rr) * HID + n0 + c];
  __syncthreads();
  unsigned short* o = out + (size_t)m * 65536;
  for (int rr = r; rr < 32; rr += 8)
    o[(size_t)(n0 + rr) * HID + k0 + c] = bfr(t[c][rr]);
}

// concat biases: [5][512] = bl|br per layer, then [768] = bq|bk|bv
__global__ __launch_bounds__(256) void prep_bias(
    const float* __restrict__ bl, const float* __restrict__ br,
    const float* __restrict__ bq, const float* __restrict__ bk,
    const float* __restrict__ bv, float* __restrict__ out) {
  int i = blockIdx.x * 256 + threadIdx.x;
  if (i < 2560) {
    int l = i >> 9, c = i & 511;
    out[i] = (c < 256) ? bl[l * 256 + c] : br[l * 256 + (c - 256)];
  } else if (i < 3328) {
    int j = i - 2560;
    out[i] = (j < 256) ? bq[j] : (j < 512) ? bk[j - 256] : bv[j - 512];
  }
}

// ---------- LayerNorm (+pre-bias)(+GELU)(+residual)(+bf16 copy) ----------
__global__ __launch_bounds__(256) void ln_act(
    const float* __restrict__ in, const float* __restrict__ pre_bias,
    const float* __restrict__ res, const float* __restrict__ gam,
    const float* __restrict__ bet, float* __restrict__ out,
    unsigned short* __restrict__ outb,
    int n_rows, int width, int do_gelu) {
  int wid = blockIdx.x * 4 + (threadIdx.x >> 6);
  int lane = threadIdx.x & 63;
  if (wid >= n_rows) return;
  int chunks = width >> 8;
  float4 v[2];
  float s = 0.f;
  for (int c = 0; c < chunks; ++c) {
    int off = c * 256 + lane * 4;
    float4 t = *(const float4*)&in[(size_t)wid * width + off];
    if (pre_bias) {
      float4 pb = *(const float4*)&pre_bias[off];
      t.x += pb.x; t.y += pb.y; t.z += pb.z; t.w += pb.w;
    }
    v[c] = t;
    s += t.x + t.y + t.z + t.w;
  }
  for (int o = 1; o < 64; o <<= 1) s += __shfl_xor(s, o);
  float mean = s / (float)width;
  float vs = 0.f;
  for (int c = 0; c < chunks; ++c) {
    float dx = v[c].x - mean, dy = v[c].y - mean, dz = v[c].z - mean, dw = v[c].w - mean;
    vs += dx * dx + dy * dy + dz * dz + dw * dw;
  }
  for (int o = 1; o < 64; o <<= 1) vs += __shfl_xor(vs, o);
  float inv = rsqrtf(vs / (float)width + 1e-5f);
  for (int c = 0; c < chunks; ++c) {
    int off = c * 256 + lane * 4;
    float4 g4 = *(const float4*)&gam[off];
    float4 b4 = *(const float4*)&bet[off];
    float y[4] = {(v[c].x - mean) * inv * g4.x + b4.x,
                  (v[c].y - mean) * inv * g4.y + b4.y,
                  (v[c].z - mean) * inv * g4.z + b4.z,
                  (v[c].w - mean) * inv * g4.w + b4.w};
    if (do_gelu) {
#pragma unroll
      for (int i = 0; i < 4; ++i) y[i] = gelu_f(y[i]);
    }
    size_t idx = (size_t)wid * width + off;
    if (res) {
      float4 r4 = *(const float4*)&res[idx];
      y[0] += r4.x; y[1] += r4.y; y[2] += r4.z; y[3] += r4.w;
    }
    float4 o4 = {y[0], y[1], y[2], y[3]};
    *(float4*)&out[idx] = o4;
    if (outb) {
      ushort4 ob = {bfr(y[0]), bfr(y[1]), bfr(y[2]), bfr(y[3])};
      *(ushort4*)&outb[idx] = ob;
    }
  }
}

// ---------- CSR build ----------
__global__ __launch_bounds__(256) void edge_count(const int* __restrict__ ei,
                                                  int* __restrict__ counts) {
  int e = blockIdx.x * 256 + threadIdx.x;
  if (e < N_EDGES) atomicAdd(&counts[ei[N_EDGES + e]], 1);
}

__global__ __launch_bounds__(1024) void scan_counts(const int* __restrict__ counts,
                                                    int* __restrict__ indptr,
                                                    int* __restrict__ cursor, int n) {
  __shared__ int sm[1024];
  __shared__ int carry;
  int tid = threadIdx.x;
  if (tid == 0) carry = 0;
  __syncthreads();
  for (int base = 0; base < n; base += 1024) {
    int i = base + tid;
    int v = (i < n) ? counts[i] : 0;
    sm[tid] = v;
    __syncthreads();
    for (int off = 1; off < 1024; off <<= 1) {
      int t = (tid >= off) ? sm[tid - off] : 0;
      __syncthreads();
      sm[tid] += t;
      __syncthreads();
    }
    int excl = sm[tid] - v + carry;
    if (i < n) { indptr[i] = excl; cursor[i] = excl; }
    int total = sm[1023];
    __syncthreads();
    if (tid == 0) carry += total;
    __syncthreads();
  }
  if (tid == 0) indptr[n] = carry;
}

__global__ __launch_bounds__(256) void edge_scatter(const int* __restrict__ ei,
                                                    int* __restrict__ cursor,
                                                    int* __restrict__ esrc) {
  int e = blockIdx.x * 256 + threadIdx.x;
  if (e < N_EDGES) {
    int d = ei[N_EDGES + e];
    int p = atomicAdd(&cursor[d], 1);
    esrc[p] = ei[e];
  }
}

// ---------- GATv2 aggregation: xlr[N][512] bf16 rows = [xl|xr] ----------
__global__ __launch_bounds__(256) void gat_agg(
    const unsigned short* __restrict__ xlr, const float* __restrict__ att,
    const int* __restrict__ indptr, const int* __restrict__ esrc,
    float* __restrict__ out) {
  int wid = blockIdx.x * 4 + (threadIdx.x >> 6);
  int lane = threadIdx.x & 63;
  if (wid >= N_NODES) return;
  float4 xri = ld4bf(&xlr[(size_t)wid * 512 + 256 + lane * 4]);
  float4 a4 = *(const float4*)&att[lane * 4];
  int beg = indptr[wid], end = indptr[wid + 1];
  float m = -INFINITY, lsum = 0.f;
  float ax = 0.f, ay = 0.f, az = 0.f, aw = 0.f;
  for (int e = beg - 1; e < end; ++e) {
    int j = (e < beg) ? wid : esrc[e];
    float4 xlj = ld4bf(&xlr[(size_t)j * 512 + lane * 4]);
    float ex = xlj.x + xri.x; ex = ex > 0.f ? ex : 0.2f * ex;
    float ey = xlj.y + xri.y; ey = ey > 0.f ? ey : 0.2f * ey;
    float ez = xlj.z + xri.z; ez = ez > 0.f ? ez : 0.2f * ez;
    float ew = xlj.w + xri.w; ew = ew > 0.f ? ew : 0.2f * ew;
    float p = ex * a4.x + ey * a4.y + ez * a4.z + ew * a4.w;
    p += __shfl_xor(p, 1); p += __shfl_xor(p, 2); p += __shfl_xor(p, 4);
    float sc = p;
    if (sc > m) {
      float f = __expf(m - sc);
      ax *= f; ay *= f; az *= f; aw *= f; lsum *= f;
      m = sc;
    }
    float w = __expf(sc - m);
    ax += w * xlj.x; ay += w * xlj.y; az += w * xlj.z; aw += w * xlj.w;
    lsum += w;
  }
  float inv = 1.f / (lsum + 1e-16f);
  float4 o = {ax * inv, ay * inv, az * inv, aw * inv};
  *(float4*)&out[(size_t)wid * HID + lane * 4] = o;
}

// ---------- TransformerConv aggregation: qkv[N][768] bf16 rows = [q|k|v] ----------
__global__ __launch_bounds__(256) void tr_agg(
    const unsigned short* __restrict__ qkv, const int* __restrict__ indptr,
    const int* __restrict__ esrc, float* __restrict__ out) {
  int wid = blockIdx.x * 4 + (threadIdx.x >> 6);
  int lane = threadIdx.x & 63;
  if (wid >= N_NODES) return;
  float4 qi = ld4bf(&qkv[(size_t)wid * 768 + lane * 4]);
  int beg = indptr[wid], end = indptr[wid + 1];
  float m = -INFINITY, lsum = 0.f;
  float ax = 0.f, ay = 0.f, az = 0.f, aw = 0.f;
  const float scale = 0.17677669529663687f;
  for (int e = beg; e < end; ++e) {
    int j = esrc[e];
    float4 kj = ld4bf(&qkv[(size_t)j * 768 + 256 + lane * 4]);
    float p = qi.x * kj.x + qi.y * kj.y + qi.z * kj.z + qi.w * kj.w;
    p += __shfl_xor(p, 1); p += __shfl_xor(p, 2); p += __shfl_xor(p, 4);
    float sc = p * scale;
    float4 vj = ld4bf(&qkv[(size_t)j * 768 + 512 + lane * 4]);
    if (sc > m) {
      float f = __expf(m - sc);
      ax *= f; ay *= f; az *= f; aw *= f; lsum *= f;
      m = sc;
    }
    float w = __expf(sc - m);
    ax += w * vj.x; ay += w * vj.y; az += w * vj.z; aw += w * vj.w;
    lsum += w;
  }
  float inv = 1.f / (lsum + 1e-16f);
  float4 o = {ax * inv, ay * inv, az * inv, aw * inv};
  *(float4*)&out[(size_t)wid * HID + lane * 4] = o;
}

// ---------- pooling over sorted batch ----------
__global__ __launch_bounds__(256) void graph_bounds(const int* __restrict__ batch,
                                                    int* __restrict__ gptr) {
  int i = blockIdx.x * 256 + threadIdx.x;
  if (i >= N_NODES) return;
  int b0 = batch[i];
  if (i == 0)
    for (int g = 0; g <= b0; ++g) gptr[g] = 0;
  int b1 = (i + 1 < N_NODES) ? batch[i + 1] : N_GRAPH;
  for (int g = b0 + 1; g <= b1; ++g) gptr[g] = i + 1;
}

__global__ __launch_bounds__(256) void pool_seg(
    const float* __restrict__ h, const int* __restrict__ gptr,
    float* __restrict__ ge) {
  int g = blockIdx.x, c = threadIdx.x;
  int s = gptr[g], e = gptr[g + 1];
  float sum = 0.f, mx = -INFINITY;
  for (int r = s; r < e; ++r) {
    float vv = h[(size_t)r * HID + c];
    sum += vv;
    mx = fmaxf(mx, vv);
  }
  int cnt = e - s;
  ge[(size_t)g * 512 + c] = sum / (float)max(cnt, 1);
  ge[(size_t)g * 512 + 256 + c] = cnt ? mx : 0.f;
}

// ---------- host ----------
static inline void gemm_launch(const float* A, const float* B, const float* bias,
                               float* C, int M, int Nn, int K, int accum,
                               hipStream_t s) {
  dim3 grid(Nn / 64, (M + 63) / 64);
  gemm_bias<<<grid, 256, 0, s>>>(A, B, bias, C, M, Nn, K, accum);
}
static inline void mfma_launch(const unsigned short* A, const unsigned short* Bt,
                               const float* bias, void* C, int M, int Nn, int K,
                               int flags, hipStream_t s) {
  dim3 grid(Nn / 128, (M + 127) / 128);
  gemm_mfma<<<grid, 256, 0, s>>>(A, Bt, bias, C, M, Nn, K, flags);
}

extern "C" void kernel_launch(void* const* d_in, const int* in_sizes, int n_in,
                              void* d_out, int out_size, void* d_ws, size_t ws_size,
                              hipStream_t stream) {
  const float* x       = (const float*)d_in[0];
  const int*   ei      = (const int*)d_in[1];
  const int*   batch   = (const int*)d_in[2];
  const float* in_W    = (const float*)d_in[3];
  const float* in_b    = (const float*)d_in[4];
  const float* in_ln_g = (const float*)d_in[5];
  const float* in_ln_b = (const float*)d_in[6];
  const float* gat_Wl  = (const float*)d_in[7];
  const float* gat_bl  = (const float*)d_in[8];
  const float* gat_Wr  = (const float*)d_in[9];
  const float* gat_br  = (const float*)d_in[10];
  const float* gat_att = (const float*)d_in[11];
  const float* gat_bias= (const float*)d_in[12];
  const float* gat_ln_g= (const float*)d_in[13];
  const float* gat_ln_b= (const float*)d_in[14];
  const float* tr_Wq   = (const float*)d_in[15];
  const float* tr_bq   = (const float*)d_in[16];
  const float* tr_Wk   = (const float*)d_in[17];
  const float* tr_bk   = (const float*)d_in[18];
  const float* tr_Wv   = (const float*)d_in[19];
  const float* tr_bv   = (const float*)d_in[20];
  const float* tr_Wsk  = (const float*)d_in[21];
  const float* tr_bsk  = (const float*)d_in[22];
  const float* tr_ln_g = (const float*)d_in[23];
  const float* tr_ln_b = (const float*)d_in[24];
  const float* out_W   = (const float*)d_in[25];
  const float* out_b   = (const float*)d_in[26];
  const float* out_ln_g= (const float*)d_in[27];
  const float* out_ln_b= (const float*)d_in[28];

  // ---- workspace (256B-aligned) ----
  char* w = (char*)d_ws;
  auto take = [&](size_t bytes) -> char* {
    char* p = w;
    w += (bytes + 255) & ~(size_t)255;
    return p;
  };
  const size_t NB = (size_t)N_NODES * HID * sizeof(float);          // 51.2 MB
  float* h    = (float*)take(NB);
  float* aggO = (float*)take(NB);                                    // agg out / skip accum
  unsigned short* hb  = (unsigned short*)take((size_t)N_NODES * HID * 2);   // 25.6 MB
  unsigned short* xq  = (unsigned short*)take((size_t)N_NODES * 768 * 2);   // 76.8 MB
  unsigned short* wbuf= (unsigned short*)take((size_t)14 * HID * HID * 2);  // 1.8 MB
  float* bcat = (float*)take(3328 * sizeof(float));
  int* indptr = (int*)take((N_NODES + 1) * sizeof(int));
  int* cursor = (int*)take(N_NODES * sizeof(int));
  int* counts = (int*)take(N_NODES * sizeof(int));
  int* esrc   = (int*)take(N_EDGES * sizeof(int));
  // pool/output scratch overlays xq (free after tr_agg)
  char* w2 = (char*)xq;
  auto take2 = [&](size_t bytes) -> char* {
    char* p = w2;
    w2 += (bytes + 255) & ~(size_t)255;
    return p;
  };
  int*   gptr = (int*)take2((N_GRAPH + 1) * sizeof(int));
  float* ge   = (float*)take2((size_t)N_GRAPH * 512 * sizeof(float));
  float* tbuf = (float*)take2((size_t)N_GRAPH * 512 * sizeof(float));

  const int EB = (N_EDGES + 255) / 256;
  const int WB = (N_NODES + 3) / 4;

  // --- weight/bias prep ---
  {
    dim3 g(8, 8, 14);
    prep_w<<<g, 256, 0, stream>>>(gat_Wl, gat_Wr, tr_Wq, tr_Wk, tr_Wv, tr_Wsk, wbuf);
    prep_bias<<<13, 256, 0, stream>>>(gat_bl, gat_br, tr_bq, tr_bk, tr_bv, bcat);
  }

  // --- CSR (dst-sorted) ---
  hipMemsetAsync(counts, 0, N_NODES * sizeof(int), stream);
  edge_count<<<EB, 256, 0, stream>>>(ei, counts);
  scan_counts<<<1, 1024, 0, stream>>>(counts, indptr, cursor, N_NODES);
  edge_scatter<<<EB, 256, 0, stream>>>(ei, cursor, esrc);

  // --- input embed ---
  gemm_launch(x, in_W, in_b, aggO, N_NODES, HID, F_INPUT, 0, stream);
  ln_act<<<WB, 256, 0, stream>>>(aggO, nullptr, nullptr, in_ln_g, in_ln_b, h, hb,
                                 N_NODES, HID, 1);

  // --- 5 GATv2 layers: fused Wl|Wr GEMM -> xq[N][512] bf16 ---
  for (int l = 0; l < NLAYER; ++l) {
    mfma_launch(hb, wbuf + (size_t)(2 * l) * 65536, bcat + l * 512, xq,
                N_NODES, 512, HID, 2, stream);
    gat_agg<<<WB, 256, 0, stream>>>(xq, gat_att + l * HID, indptr, esrc, aggO);
    ln_act<<<WB, 256, 0, stream>>>(aggO, gat_bias + l * HID, h,
                                   gat_ln_g + l * HID, gat_ln_b + l * HID, h, hb,
                                   N_NODES, HID, 1);
  }

  // --- TransformerConv: fused q|k|v GEMM -> xq[N][768] bf16 ---
  mfma_launch(hb, wbuf + (size_t)10 * 65536, bcat + 2560, xq,
              N_NODES, 768, HID, 2, stream);
  tr_agg<<<WB, 256, 0, stream>>>(xq, indptr, esrc, aggO);
  mfma_launch(hb, wbuf + (size_t)13 * 65536, tr_bsk, aggO,
              N_NODES, HID, HID, 1, stream);  // += skip (fp32 accum)
  ln_act<<<WB, 256, 0, stream>>>(aggO, nullptr, h, tr_ln_g, tr_ln_b, h, nullptr,
                                 N_NODES, HID, 0);

  // --- pooling (sorted batch; scratch overlays xq, now free) ---
  graph_bounds<<<(N_NODES + 255) / 256, 256, 0, stream>>>(batch, gptr);
  pool_seg<<<N_GRAPH, 256, 0, stream>>>(h, gptr, ge);

  // --- output proj ---
  gemm_launch(ge, out_W, out_b, tbuf, N_GRAPH, 512, 512, 0, stream);
  ln_act<<<(N_GRAPH + 3) / 4, 256, 0, stream>>>(tbuf, nullptr, nullptr,
                                                out_ln_g, out_ln_b, (float*)d_out,
                                                nullptr, N_GRAPH, 512, 1);
}

// Round 5
// 1242.396 us; speedup vs baseline: 2.9946x; 1.5194x over previous
//
#include <hip/hip_runtime.h>
#include <math.h>

#define N_NODES 50000
#define N_EDGES 800000
#define N_GRAPH 2000
#define F_INPUT 34
#define HID 256
#define NLAYER 5

typedef __attribute__((ext_vector_type(8))) short short8;
typedef __attribute__((ext_vector_type(4))) float float4v;

// ---------- helpers ----------
__device__ __forceinline__ float gelu_f(float x) {
  return 0.5f * x * (1.0f + erff(x * 0.70710678118654752440f));
}
__device__ __forceinline__ unsigned short bfr(float f) {  // fp32 -> bf16 RNE
  unsigned u = __float_as_uint(f);
  return (unsigned short)((u + 0x7fffu + ((u >> 16) & 1u)) >> 16);
}
__device__ __forceinline__ float b2f(unsigned short s) {
  return __uint_as_float(((unsigned)s) << 16);
}
__device__ __forceinline__ float4 ld4bf(const unsigned short* p) {
  ushort4 u = *(const ushort4*)p;
  float4 f;
  f.x = b2f(u.x); f.y = b2f(u.y); f.z = b2f(u.z); f.w = b2f(u.w);
  return f;
}

// ---------- fp32 GEMM (input embed K=34) ----------
__global__ __launch_bounds__(256) void gemm_bias(
    const float* __restrict__ A, const float* __restrict__ B,
    const float* __restrict__ bias, float* __restrict__ C,
    int M, int Nn, int K, int accum) {
  __shared__ float As[16][64];
  __shared__ float Bs[16][64];
  int tid = threadIdx.x;
  int tx = tid & 15, ty = tid >> 4;
  int row0 = blockIdx.y * 64;
  int col0 = blockIdx.x * 64;
  float acc[4][4] = {};
  int a_r = tid >> 2;
  int a_c = (tid & 3) * 4;
  int b_r = tid >> 4;
  int b_c = (tid & 15) * 4;

  for (int k0 = 0; k0 < K; k0 += 16) {
    int ar = row0 + a_r;
#pragma unroll
    for (int i = 0; i < 4; ++i) {
      int kc = k0 + a_c + i;
      As[a_c + i][a_r] = (ar < M && kc < K) ? A[(long)ar * K + kc] : 0.f;
    }
    int bk = k0 + b_r;
    if (bk < K) {
      float4 bv = *(const float4*)&B[(long)bk * Nn + col0 + b_c];
      Bs[b_r][b_c + 0] = bv.x; Bs[b_r][b_c + 1] = bv.y;
      Bs[b_r][b_c + 2] = bv.z; Bs[b_r][b_c + 3] = bv.w;
    } else {
      Bs[b_r][b_c + 0] = 0.f; Bs[b_r][b_c + 1] = 0.f;
      Bs[b_r][b_c + 2] = 0.f; Bs[b_r][b_c + 3] = 0.f;
    }
    __syncthreads();
#pragma unroll
    for (int kk = 0; kk < 16; ++kk) {
      float4 a = *(const float4*)&As[kk][ty * 4];
      float4 b = *(const float4*)&Bs[kk][tx * 4];
      float av[4] = {a.x, a.y, a.z, a.w};
      float bv[4] = {b.x, b.y, b.z, b.w};
#pragma unroll
      for (int i = 0; i < 4; ++i)
#pragma unroll
        for (int j = 0; j < 4; ++j) acc[i][j] += av[i] * bv[j];
    }
    __syncthreads();
  }
  float4 bi = *(const float4*)&bias[col0 + tx * 4];
  float bia[4] = {bi.x, bi.y, bi.z, bi.w};
#pragma unroll
  for (int i = 0; i < 4; ++i) {
    int r = row0 + ty * 4 + i;
    if (r < M) {
      float4* cp = (float4*)&C[(long)r * Nn + col0 + tx * 4];
      float4 o;
      o.x = acc[i][0] + bia[0]; o.y = acc[i][1] + bia[1];
      o.z = acc[i][2] + bia[2]; o.w = acc[i][3] + bia[3];
      if (accum) {
        float4 old = *cp;
        o.x += old.x; o.y += old.y; o.z += old.z; o.w += old.w;
      }
      *cp = o;
    }
  }
}

// ---------- bf16 MFMA GEMM ----------
// A: [M][K] bf16 ; Bt: [Nn][K] bf16 ; bias fp32.
// flags: bit0 = accumulate into fp32 C ; bit1 = write bf16 (LDS-coalesced).
__global__ __launch_bounds__(256) void gemm_mfma(
    const unsigned short* __restrict__ A, const unsigned short* __restrict__ Bt,
    const float* __restrict__ bias, void* __restrict__ Cv,
    int M, int Nn, int K, int flags) {
  __shared__ unsigned short smem[10240];  // As=[128][40] @0, Bs=[128][40] @5120
#define AS(r, c) smem[(r) * 40 + (c)]
#define BS(r, c) smem[5120 + (r) * 40 + (c)]
  int tid = threadIdx.x;
  int wave = tid >> 6, lane = tid & 63;
  int row0 = blockIdx.y * 128;
  int col0 = blockIdx.x * 128;
  int wm0 = (wave >> 1) * 64;
  int wn0 = (wave & 1) * 64;
  int lr = tid >> 2;
  int lc = (tid & 3) * 8;
  int q = lane >> 4;
  int ln = lane & 15;

  float4v acc[4][4];
#pragma unroll
  for (int i = 0; i < 4; ++i)
#pragma unroll
    for (int j = 0; j < 4; ++j) acc[i][j] = (float4v)0.f;

  for (int k0 = 0; k0 < K; k0 += 32) {
    int r1 = row0 + lr, r2 = row0 + lr + 64;
    uint4 za = {0u, 0u, 0u, 0u};
    uint4 va = (r1 < M) ? *(const uint4*)&A[(size_t)r1 * K + k0 + lc] : za;
    uint4 vb = (r2 < M) ? *(const uint4*)&A[(size_t)r2 * K + k0 + lc] : za;
    uint4 wa = *(const uint4*)&Bt[(size_t)(col0 + lr) * K + k0 + lc];
    uint4 wb = *(const uint4*)&Bt[(size_t)(col0 + lr + 64) * K + k0 + lc];
    *(uint4*)&AS(lr, lc) = va;
    *(uint4*)&AS(lr + 64, lc) = vb;
    *(uint4*)&BS(lr, lc) = wa;
    *(uint4*)&BS(lr + 64, lc) = wb;
    __syncthreads();
    short8 af[4], bf[4];
#pragma unroll
    for (int i = 0; i < 4; ++i) af[i] = *(const short8*)&AS(wm0 + i * 16 + ln, q * 8);
#pragma unroll
    for (int j = 0; j < 4; ++j) bf[j] = *(const short8*)&BS(wn0 + j * 16 + ln, q * 8);
#pragma unroll
    for (int i = 0; i < 4; ++i)
#pragma unroll
      for (int j = 0; j < 4; ++j)
        acc[i][j] = __builtin_amdgcn_mfma_f32_16x16x32_bf16(af[i], bf[j], acc[i][j], 0, 0, 0);
    __syncthreads();
  }
  int rb = (lane >> 4) * 4;
  if (flags & 2) {
    // LDS-transposed coalesced bf16 epilogue: per-wave 64x64 tile in 2 passes
    unsigned short* Cb = (unsigned short*)Cv;
    unsigned short* eb = smem + wave * 2560;  // 64 rows x stride 40
#pragma unroll
    for (int p = 0; p < 2; ++p) {
#pragma unroll
      for (int jj = 0; jj < 2; ++jj) {
        int j = p * 2 + jj;
        float bv = bias[col0 + wn0 + j * 16 + ln];
#pragma unroll
        for (int i = 0; i < 4; ++i)
#pragma unroll
          for (int r = 0; r < 4; ++r)
            eb[(i * 16 + rb + r) * 40 + jj * 16 + ln] = bfr(acc[i][j][r] + bv);
      }
      int grow = row0 + wm0 + lane;
      uint4 w0 = *(uint4*)&eb[lane * 40 + 0];
      uint4 w1 = *(uint4*)&eb[lane * 40 + 8];
      uint4 w2 = *(uint4*)&eb[lane * 40 + 16];
      uint4 w3 = *(uint4*)&eb[lane * 40 + 24];
      if (grow < M) {
        unsigned short* dst = Cb + (size_t)grow * Nn + col0 + wn0 + p * 32;
        *(uint4*)&dst[0] = w0;
        *(uint4*)&dst[8] = w1;
        *(uint4*)&dst[16] = w2;
        *(uint4*)&dst[24] = w3;
      }
    }
  } else {
    float* C = (float*)Cv;
#pragma unroll
    for (int j = 0; j < 4; ++j) {
      int col = col0 + wn0 + j * 16 + ln;
      float bv = bias[col];
#pragma unroll
      for (int i = 0; i < 4; ++i)
#pragma unroll
        for (int r = 0; r < 4; ++r) {
          int row = row0 + wm0 + i * 16 + rb + r;
          if (row < M) {
            float v = acc[i][j][r] + bv;
            if (flags & 1) v += C[(size_t)row * Nn + col];
            C[(size_t)row * Nn + col] = v;
          }
        }
    }
  }
#undef AS
#undef BS
}

// ---------- weight prep: Wt_bf16[n][k] = bf16(W[k][n]) ----------
// slots: 2l=Wl_l, 2l+1=Wr_l (l<5); 10=q, 11=k, 12=v, 13=skip
__global__ __launch_bounds__(256) void prep_w(
    const float* __restrict__ Wl, const float* __restrict__ Wr,
    const float* __restrict__ Wq, const float* __restrict__ Wk,
    const float* __restrict__ Wv, const float* __restrict__ Wsk,
    unsigned short* __restrict__ out) {
  __shared__ float t[32][33];
  int m = blockIdx.z;
  const float* W = (m < 10) ? (((m & 1) ? Wr : Wl) + (size_t)(m >> 1) * 65536)
                 : (m == 10) ? Wq : (m == 11) ? Wk : (m == 12) ? Wv : Wsk;
  int k0 = blockIdx.y * 32, n0 = blockIdx.x * 32;
  int r = threadIdx.x >> 5, c = threadIdx.x & 31;
  for (int rr = r; rr < 32; rr += 8)
    t[rr][c] = W[(size_t)(k0 + rr) * HID + n0 + c];
  __syncthreads();
  unsigned short* o = out + (size_t)m * 65536;
  for (int rr = r; rr < 32; rr += 8)
    o[(size_t)(n0 + rr) * HID + k0 + c] = bfr(t[c][rr]);
}

// out_W [512][512] -> bf16 transpose
__global__ __launch_bounds__(256) void prep_wout(const float* __restrict__ W,
                                                 unsigned short* __restrict__ o) {
  __shared__ float t[32][33];
  int k0 = blockIdx.y * 32, n0 = blockIdx.x * 32;
  int r = threadIdx.x >> 5, c = threadIdx.x & 31;
  for (int rr = r; rr < 32; rr += 8)
    t[rr][c] = W[(size_t)(k0 + rr) * 512 + n0 + c];
  __syncthreads();
  for (int rr = r; rr < 32; rr += 8)
    o[(size_t)(n0 + rr) * 512 + k0 + c] = bfr(t[c][rr]);
}

// concat biases: [5][512] = bl|br per layer, then [768] = bq|bk|bv
__global__ __launch_bounds__(256) void prep_bias(
    const float* __restrict__ bl, const float* __restrict__ br,
    const float* __restrict__ bq, const float* __restrict__ bk,
    const float* __restrict__ bv, float* __restrict__ out) {
  int i = blockIdx.x * 256 + threadIdx.x;
  if (i < 2560) {
    int l = i >> 9, c = i & 511;
    out[i] = (c < 256) ? bl[l * 256 + c] : br[l * 256 + (c - 256)];
  } else if (i < 3328) {
    int j = i - 2560;
    out[i] = (j < 256) ? bq[j] : (j < 512) ? bk[j - 256] : bv[j - 512];
  }
}

// ---------- LayerNorm standalone (embed + final out) ----------
__global__ __launch_bounds__(256) void ln_act(
    const float* __restrict__ in, const float* __restrict__ gam,
    const float* __restrict__ bet, float* __restrict__ out,
    unsigned short* __restrict__ outb,
    int n_rows, int width, int do_gelu) {
  int wid = blockIdx.x * 4 + (threadIdx.x >> 6);
  int lane = threadIdx.x & 63;
  if (wid >= n_rows) return;
  int chunks = width >> 8;
  float4 v[2];
  float s = 0.f;
  for (int c = 0; c < chunks; ++c) {
    int off = c * 256 + lane * 4;
    float4 t = *(const float4*)&in[(size_t)wid * width + off];
    v[c] = t;
    s += t.x + t.y + t.z + t.w;
  }
  for (int o = 1; o < 64; o <<= 1) s += __shfl_xor(s, o);
  float mean = s / (float)width;
  float vs = 0.f;
  for (int c = 0; c < chunks; ++c) {
    float dx = v[c].x - mean, dy = v[c].y - mean, dz = v[c].z - mean, dw = v[c].w - mean;
    vs += dx * dx + dy * dy + dz * dz + dw * dw;
  }
  for (int o = 1; o < 64; o <<= 1) vs += __shfl_xor(vs, o);
  float inv = rsqrtf(vs / (float)width + 1e-5f);
  for (int c = 0; c < chunks; ++c) {
    int off = c * 256 + lane * 4;
    float4 g4 = *(const float4*)&gam[off];
    float4 b4 = *(const float4*)&bet[off];
    float y[4] = {(v[c].x - mean) * inv * g4.x + b4.x,
                  (v[c].y - mean) * inv * g4.y + b4.y,
                  (v[c].z - mean) * inv * g4.z + b4.z,
                  (v[c].w - mean) * inv * g4.w + b4.w};
    if (do_gelu) {
#pragma unroll
      for (int i = 0; i < 4; ++i) y[i] = gelu_f(y[i]);
    }
    size_t idx = (size_t)wid * width + off;
    float4 o4 = {y[0], y[1], y[2], y[3]};
    *(float4*)&out[idx] = o4;
    if (outb) {
      ushort4 ob = {bfr(y[0]), bfr(y[1]), bfr(y[2]), bfr(y[3])};
      *(ushort4*)&outb[idx] = ob;
    }
  }
}

// ---------- CSR build (two-level scan) ----------
__global__ __launch_bounds__(256) void edge_count(const int* __restrict__ ei,
                                                  int* __restrict__ counts) {
  int e = blockIdx.x * 256 + threadIdx.x;
  if (e < N_EDGES) atomicAdd(&counts[ei[N_EDGES + e]], 1);
}

__global__ __launch_bounds__(1024) void scan1(const int* __restrict__ counts,
                                              int* __restrict__ indptr,
                                              int* __restrict__ bsums, int n) {
  __shared__ int sm[1024];
  int tid = threadIdx.x;
  int i = blockIdx.x * 1024 + tid;
  int v = (i < n) ? counts[i] : 0;
  sm[tid] = v;
  __syncthreads();
  for (int off = 1; off < 1024; off <<= 1) {
    int t = (tid >= off) ? sm[tid - off] : 0;
    __syncthreads();
    sm[tid] += t;
    __syncthreads();
  }
  if (i < n) indptr[i] = sm[tid] - v;  // block-local exclusive
  if (tid == 1023) bsums[blockIdx.x] = sm[1023];
}

__global__ void scan2(int* __restrict__ bsums, int nb) {
  if (threadIdx.x == 0 && blockIdx.x == 0) {
    int acc = 0;
    for (int i = 0; i < nb; ++i) { int t = bsums[i]; bsums[i] = acc; acc += t; }
  }
}

__global__ __launch_bounds__(256) void scan3(const int* __restrict__ bsums,
                                             int* __restrict__ indptr,
                                             int* __restrict__ cursor, int n) {
  int i = blockIdx.x * 256 + threadIdx.x;
  if (i < n) {
    int v = indptr[i] + bsums[i >> 10];
    indptr[i] = v;
    cursor[i] = v;
  }
  if (i == 0) indptr[n] = N_EDGES;
}

__global__ __launch_bounds__(256) void edge_scatter(const int* __restrict__ ei,
                                                    int* __restrict__ cursor,
                                                    int* __restrict__ esrc) {
  int e = blockIdx.x * 256 + threadIdx.x;
  if (e < N_EDGES) {
    int d = ei[N_EDGES + e];
    int p = atomicAdd(&cursor[d], 1);
    esrc[p] = ei[e];
  }
}

// ---------- GATv2 agg + bias + LN + GELU + residual (fused) ----------
// xlr[N][512] bf16 rows = [xl|xr]; writes h (fp32) and hb (bf16).
__global__ __launch_bounds__(256) void gat_agg(
    const unsigned short* __restrict__ xlr, const float* __restrict__ att,
    const int* __restrict__ indptr, const int* __restrict__ esrc,
    const float* __restrict__ pre_bias, const float* __restrict__ gam,
    const float* __restrict__ bet, float* __restrict__ h,
    unsigned short* __restrict__ hb) {
  int wid = blockIdx.x * 4 + (threadIdx.x >> 6);
  int lane = threadIdx.x & 63;
  if (wid >= N_NODES) return;
  float4 xri = ld4bf(&xlr[(size_t)wid * 512 + 256 + lane * 4]);
  float4 a4 = *(const float4*)&att[lane * 4];
  int beg = indptr[wid], end = indptr[wid + 1];

  float m, lsum, ax, ay, az, aw;
  {  // self loop (always present) initializes the online softmax
    float4 f = ld4bf(&xlr[(size_t)wid * 512 + lane * 4]);
    float ex = f.x + xri.x; ex = ex > 0.f ? ex : 0.2f * ex;
    float ey = f.y + xri.y; ey = ey > 0.f ? ey : 0.2f * ey;
    float ez = f.z + xri.z; ez = ez > 0.f ? ez : 0.2f * ez;
    float ew = f.w + xri.w; ew = ew > 0.f ? ew : 0.2f * ew;
    float p = ex * a4.x + ey * a4.y + ez * a4.z + ew * a4.w;
    p += __shfl_xor(p, 1); p += __shfl_xor(p, 2); p += __shfl_xor(p, 4);
    m = p; lsum = 1.f;
    ax = f.x; ay = f.y; az = f.z; aw = f.w;
  }
  int e = beg;
  for (; e + 1 < end; e += 2) {  // pairwise: 2 gathers in flight
    int j0 = esrc[e], j1 = esrc[e + 1];
    float4 f0 = ld4bf(&xlr[(size_t)j0 * 512 + lane * 4]);
    float4 f1 = ld4bf(&xlr[(size_t)j1 * 512 + lane * 4]);
    {
      float ex = f0.x + xri.x; ex = ex > 0.f ? ex : 0.2f * ex;
      float ey = f0.y + xri.y; ey = ey > 0.f ? ey : 0.2f * ey;
      float ez = f0.z + xri.z; ez = ez > 0.f ? ez : 0.2f * ez;
      float ew = f0.w + xri.w; ew = ew > 0.f ? ew : 0.2f * ew;
      float p = ex * a4.x + ey * a4.y + ez * a4.z + ew * a4.w;
      p += __shfl_xor(p, 1); p += __shfl_xor(p, 2); p += __shfl_xor(p, 4);
      if (p > m) {
        float f = __expf(m - p);
        ax *= f; ay *= f; az *= f; aw *= f; lsum *= f; m = p;
      }
      float w = __expf(p - m);
      ax += w * f0.x; ay += w * f0.y; az += w * f0.z; aw += w * f0.w;
      lsum += w;
    }
    {
      float ex = f1.x + xri.x; ex = ex > 0.f ? ex : 0.2f * ex;
      float ey = f1.y + xri.y; ey = ey > 0.f ? ey : 0.2f * ey;
      float ez = f1.z + xri.z; ez = ez > 0.f ? ez : 0.2f * ez;
      float ew = f1.w + xri.w; ew = ew > 0.f ? ew : 0.2f * ew;
      float p = ex * a4.x + ey * a4.y + ez * a4.z + ew * a4.w;
      p += __shfl_xor(p, 1); p += __shfl_xor(p, 2); p += __shfl_xor(p, 4);
      if (p > m) {
        float f = __expf(m - p);
        ax *= f; ay *= f; az *= f; aw *= f; lsum *= f; m = p;
      }
      float w = __expf(p - m);
      ax += w * f1.x; ay += w * f1.y; az += w * f1.z; aw += w * f1.w;
      lsum += w;
    }
  }
  if (e < end) {
    int j = esrc[e];
    float4 f = ld4bf(&xlr[(size_t)j * 512 + lane * 4]);
    float ex = f.x + xri.x; ex = ex > 0.f ? ex : 0.2f * ex;
    float ey = f.y + xri.y; ey = ey > 0.f ? ey : 0.2f * ey;
    float ez = f.z + xri.z; ez = ez > 0.f ? ez : 0.2f * ez;
    float ew = f.w + xri.w; ew = ew > 0.f ? ew : 0.2f * ew;
    float p = ex * a4.x + ey * a4.y + ez * a4.z + ew * a4.w;
    p += __shfl_xor(p, 1); p += __shfl_xor(p, 2); p += __shfl_xor(p, 4);
    if (p > m) {
      float f2 = __expf(m - p);
      ax *= f2; ay *= f2; az *= f2; aw *= f2; lsum *= f2; m = p;
    }
    float w = __expf(p - m);
    ax += w * f.x; ay += w * f.y; az += w * f.z; aw += w * f.w;
    lsum += w;
  }
  float inv = 1.f / (lsum + 1e-16f);
  float4 pb = *(const float4*)&pre_bias[lane * 4];
  float y0 = ax * inv + pb.x, y1 = ay * inv + pb.y;
  float y2 = az * inv + pb.z, y3 = aw * inv + pb.w;
  // LN over 256
  float s = y0 + y1 + y2 + y3;
  for (int o = 1; o < 64; o <<= 1) s += __shfl_xor(s, o);
  float mean = s * (1.f / 256.f);
  float d0 = y0 - mean, d1 = y1 - mean, d2 = y2 - mean, d3 = y3 - mean;
  float vs = d0 * d0 + d1 * d1 + d2 * d2 + d3 * d3;
  for (int o = 1; o < 64; o <<= 1) vs += __shfl_xor(vs, o);
  float inv2 = rsqrtf(vs * (1.f / 256.f) + 1e-5f);
  float4 g4 = *(const float4*)&gam[lane * 4];
  float4 b4 = *(const float4*)&bet[lane * 4];
  y0 = gelu_f(d0 * inv2 * g4.x + b4.x);
  y1 = gelu_f(d1 * inv2 * g4.y + b4.y);
  y2 = gelu_f(d2 * inv2 * g4.z + b4.z);
  y3 = gelu_f(d3 * inv2 * g4.w + b4.w);
  size_t idx = (size_t)wid * HID + lane * 4;
  float4 r4 = *(const float4*)&h[idx];
  y0 += r4.x; y1 += r4.y; y2 += r4.z; y3 += r4.w;
  float4 o4 = {y0, y1, y2, y3};
  *(float4*)&h[idx] = o4;
  ushort4 ob = {bfr(y0), bfr(y1), bfr(y2), bfr(y3)};
  *(ushort4*)&hb[idx] = ob;
}

// ---------- TransformerConv agg + skip + LN + residual (fused) ----------
// qkv[N][768] bf16 rows = [q|k|v]; skip[N][256] fp32 = h@Wsk + bsk.
__global__ __launch_bounds__(256) void tr_agg(
    const unsigned short* __restrict__ qkv, const int* __restrict__ indptr,
    const int* __restrict__ esrc, const float* __restrict__ skip,
    const float* __restrict__ gam, const float* __restrict__ bet,
    float* __restrict__ h) {
  int wid = blockIdx.x * 4 + (threadIdx.x >> 6);
  int lane = threadIdx.x & 63;
  if (wid >= N_NODES) return;
  float4 qi = ld4bf(&qkv[(size_t)wid * 768 + lane * 4]);
  int beg = indptr[wid], end = indptr[wid + 1];
  float m = -INFINITY, lsum = 0.f;
  float ax = 0.f, ay = 0.f, az = 0.f, aw = 0.f;
  const float scale = 0.17677669529663687f;
  int e = beg;
  for (; e + 1 < end; e += 2) {  // pairwise: 4 gathers in flight
    int j0 = esrc[e], j1 = esrc[e + 1];
    float4 k0 = ld4bf(&qkv[(size_t)j0 * 768 + 256 + lane * 4]);
    float4 v0 = ld4bf(&qkv[(size_t)j0 * 768 + 512 + lane * 4]);
    float4 k1 = ld4bf(&qkv[(size_t)j1 * 768 + 256 + lane * 4]);
    float4 v1 = ld4bf(&qkv[(size_t)j1 * 768 + 512 + lane * 4]);
    {
      float p = qi.x * k0.x + qi.y * k0.y + qi.z * k0.z + qi.w * k0.w;
      p += __shfl_xor(p, 1); p += __shfl_xor(p, 2); p += __shfl_xor(p, 4);
      float sc = p * scale;
      if (sc > m) {
        float f = __expf(m - sc);
        ax *= f; ay *= f; az *= f; aw *= f; lsum *= f; m = sc;
      }
      float w = __expf(sc - m);
      ax += w * v0.x; ay += w * v0.y; az += w * v0.z; aw += w * v0.w;
      lsum += w;
    }
    {
      float p = qi.x * k1.x + qi.y * k1.y + qi.z * k1.z + qi.w * k1.w;
      p += __shfl_xor(p, 1); p += __shfl_xor(p, 2); p += __shfl_xor(p, 4);
      float sc = p * scale;
      if (sc > m) {
        float f = __expf(m - sc);
        ax *= f; ay *= f; az *= f; aw *= f; lsum *= f; m = sc;
      }
      float w = __expf(sc - m);
      ax += w * v1.x; ay += w * v1.y; az += w * v1.z; aw += w * v1.w;
      lsum += w;
    }
  }
  if (e < end) {
    int j = esrc[e];
    float4 kj = ld4bf(&qkv[(size_t)j * 768 + 256 + lane * 4]);
    float4 vj = ld4bf(&qkv[(size_t)j * 768 + 512 + lane * 4]);
    float p = qi.x * kj.x + qi.y * kj.y + qi.z * kj.z + qi.w * kj.w;
    p += __shfl_xor(p, 1); p += __shfl_xor(p, 2); p += __shfl_xor(p, 4);
    float sc = p * scale;
    if (sc > m) {
      float f = __expf(m - sc);
      ax *= f; ay *= f; az *= f; aw *= f; lsum *= f; m = sc;
    }
    float w = __expf(sc - m);
    ax += w * vj.x; ay += w * vj.y; az += w * vj.z; aw += w * vj.w;
    lsum += w;
  }
  float inv = 1.f / (lsum + 1e-16f);
  size_t idx = (size_t)wid * HID + lane * 4;
  float4 sk = *(const float4*)&skip[idx];
  float y0 = ax * inv + sk.x, y1 = ay * inv + sk.y;
  float y2 = az * inv + sk.z, y3 = aw * inv + sk.w;
  // LN over 256 (no gelu)
  float s = y0 + y1 + y2 + y3;
  for (int o = 1; o < 64; o <<= 1) s += __shfl_xor(s, o);
  float mean = s * (1.f / 256.f);
  float d0 = y0 - mean, d1 = y1 - mean, d2 = y2 - mean, d3 = y3 - mean;
  float vs = d0 * d0 + d1 * d1 + d2 * d2 + d3 * d3;
  for (int o = 1; o < 64; o <<= 1) vs += __shfl_xor(vs, o);
  float inv2 = rsqrtf(vs * (1.f / 256.f) + 1e-5f);
  float4 g4 = *(const float4*)&gam[lane * 4];
  float4 b4 = *(const float4*)&bet[lane * 4];
  float4 r4 = *(const float4*)&h[idx];
  float4 o4;
  o4.x = r4.x + d0 * inv2 * g4.x + b4.x;
  o4.y = r4.y + d1 * inv2 * g4.y + b4.y;
  o4.z = r4.z + d2 * inv2 * g4.z + b4.z;
  o4.w = r4.w + d3 * inv2 * g4.w + b4.w;
  *(float4*)&h[idx] = o4;
}

// ---------- pooling over sorted batch ----------
__global__ __launch_bounds__(256) void graph_bounds(const int* __restrict__ batch,
                                                    int* __restrict__ gptr) {
  int i = blockIdx.x * 256 + threadIdx.x;
  if (i >= N_NODES) return;
  int b0 = batch[i];
  if (i == 0)
    for (int g = 0; g <= b0; ++g) gptr[g] = 0;
  int b1 = (i + 1 < N_NODES) ? batch[i + 1] : N_GRAPH;
  for (int g = b0 + 1; g <= b1; ++g) gptr[g] = i + 1;
}

__global__ __launch_bounds__(256) void pool_seg(
    const float* __restrict__ h, const int* __restrict__ gptr,
    unsigned short* __restrict__ geb) {
  int g = blockIdx.x, c = threadIdx.x;
  int s = gptr[g], e = gptr[g + 1];
  float sum = 0.f, mx = -INFINITY;
  for (int r = s; r < e; ++r) {
    float vv = h[(size_t)r * HID + c];
    sum += vv;
    mx = fmaxf(mx, vv);
  }
  int cnt = e - s;
  geb[(size_t)g * 512 + c] = bfr(sum / (float)max(cnt, 1));
  geb[(size_t)g * 512 + 256 + c] = bfr(cnt ? mx : 0.f);
}

// ---------- host ----------
static inline void gemm_launch(const float* A, const float* B, const float* bias,
                               float* C, int M, int Nn, int K, int accum,
                               hipStream_t s) {
  dim3 grid(Nn / 64, (M + 63) / 64);
  gemm_bias<<<grid, 256, 0, s>>>(A, B, bias, C, M, Nn, K, accum);
}
static inline void mfma_launch(const unsigned short* A, const unsigned short* Bt,
                               const float* bias, void* C, int M, int Nn, int K,
                               int flags, hipStream_t s) {
  dim3 grid(Nn / 128, (M + 127) / 128);
  gemm_mfma<<<grid, 256, 0, s>>>(A, Bt, bias, C, M, Nn, K, flags);
}

extern "C" void kernel_launch(void* const* d_in, const int* in_sizes, int n_in,
                              void* d_out, int out_size, void* d_ws, size_t ws_size,
                              hipStream_t stream) {
  const float* x       = (const float*)d_in[0];
  const int*   ei      = (const int*)d_in[1];
  const int*   batch   = (const int*)d_in[2];
  const float* in_W    = (const float*)d_in[3];
  const float* in_b    = (const float*)d_in[4];
  const float* in_ln_g = (const float*)d_in[5];
  const float* in_ln_b = (const float*)d_in[6];
  const float* gat_Wl  = (const float*)d_in[7];
  const float* gat_bl  = (const float*)d_in[8];
  const float* gat_Wr  = (const float*)d_in[9];
  const float* gat_br  = (const float*)d_in[10];
  const float* gat_att = (const float*)d_in[11];
  const float* gat_bias= (const float*)d_in[12];
  const float* gat_ln_g= (const float*)d_in[13];
  const float* gat_ln_b= (const float*)d_in[14];
  const float* tr_Wq   = (const float*)d_in[15];
  const float* tr_bq   = (const float*)d_in[16];
  const float* tr_Wk   = (const float*)d_in[17];
  const float* tr_bk   = (const float*)d_in[18];
  const float* tr_Wv   = (const float*)d_in[19];
  const float* tr_bv   = (const float*)d_in[20];
  const float* tr_Wsk  = (const float*)d_in[21];
  const float* tr_bsk  = (const float*)d_in[22];
  const float* tr_ln_g = (const float*)d_in[23];
  const float* tr_ln_b = (const float*)d_in[24];
  const float* out_W   = (const float*)d_in[25];
  const float* out_b   = (const float*)d_in[26];
  const float* out_ln_g= (const float*)d_in[27];
  const float* out_ln_b= (const float*)d_in[28];

  // ---- workspace (256B-aligned) ----
  char* w = (char*)d_ws;
  auto take = [&](size_t bytes) -> char* {
    char* p = w;
    w += (bytes + 255) & ~(size_t)255;
    return p;
  };
  const size_t NB = (size_t)N_NODES * HID * sizeof(float);
  float* h    = (float*)take(NB);                                    // 51.2 MB
  float* aggO = (float*)take(NB);                                    // skip / embed tmp
  unsigned short* hb  = (unsigned short*)take((size_t)N_NODES * HID * 2);   // 25.6 MB
  unsigned short* xq  = (unsigned short*)take((size_t)N_NODES * 768 * 2);   // 76.8 MB
  unsigned short* wbuf= (unsigned short*)take((size_t)(14 * 65536 + 262144) * 2);
  float* bcat = (float*)take(3328 * sizeof(float));
  int* indptr = (int*)take((N_NODES + 1) * sizeof(int));
  int* cursor = (int*)take(N_NODES * sizeof(int));
  int* counts = (int*)take(N_NODES * sizeof(int));
  int* esrc   = (int*)take(N_EDGES * sizeof(int));
  int* bsums  = (int*)take(64 * sizeof(int));
  // pool/output scratch overlays xq (free after tr_agg)
  char* w2 = (char*)xq;
  auto take2 = [&](size_t bytes) -> char* {
    char* p = w2;
    w2 += (bytes + 255) & ~(size_t)255;
    return p;
  };
  int* gptr = (int*)take2((N_GRAPH + 1) * sizeof(int));
  unsigned short* geb = (unsigned short*)take2((size_t)N_GRAPH * 512 * 2);
  float* tbuf = (float*)take2((size_t)N_GRAPH * 512 * sizeof(float));

  const int EB = (N_EDGES + 255) / 256;
  const int WB = (N_NODES + 3) / 4;
  const int NSB = (N_NODES + 1023) / 1024;  // 49 scan blocks

  // --- weight/bias prep ---
  {
    dim3 g(8, 8, 14);
    prep_w<<<g, 256, 0, stream>>>(gat_Wl, gat_Wr, tr_Wq, tr_Wk, tr_Wv, tr_Wsk, wbuf);
    dim3 g2(16, 16);
    prep_wout<<<g2, 256, 0, stream>>>(out_W, wbuf + (size_t)14 * 65536);
    prep_bias<<<13, 256, 0, stream>>>(gat_bl, gat_br, tr_bq, tr_bk, tr_bv, bcat);
  }

  // --- CSR (dst-sorted), two-level scan ---
  hipMemsetAsync(counts, 0, N_NODES * sizeof(int), stream);
  edge_count<<<EB, 256, 0, stream>>>(ei, counts);
  scan1<<<NSB, 1024, 0, stream>>>(counts, indptr, bsums, N_NODES);
  scan2<<<1, 64, 0, stream>>>(bsums, NSB);
  scan3<<<(N_NODES + 255) / 256, 256, 0, stream>>>(bsums, indptr, cursor, N_NODES);
  edge_scatter<<<EB, 256, 0, stream>>>(ei, cursor, esrc);

  // --- input embed: h = gelu(LN(x @ in_W + in_b)), hb = bf16(h) ---
  gemm_launch(x, in_W, in_b, aggO, N_NODES, HID, F_INPUT, 0, stream);
  ln_act<<<WB, 256, 0, stream>>>(aggO, in_ln_g, in_ln_b, h, hb, N_NODES, HID, 1);

  // --- 5 GATv2 layers: fused Wl|Wr GEMM -> xq[N][512] bf16; fused agg+LN ---
  for (int l = 0; l < NLAYER; ++l) {
    mfma_launch(hb, wbuf + (size_t)(2 * l) * 65536, bcat + l * 512, xq,
                N_NODES, 512, HID, 2, stream);
    gat_agg<<<WB, 256, 0, stream>>>(xq, gat_att + l * HID, indptr, esrc,
                                    gat_bias + l * HID, gat_ln_g + l * HID,
                                    gat_ln_b + l * HID, h, hb);
  }

  // --- TransformerConv: skip GEMM first, then fused q|k|v GEMM + agg+LN ---
  mfma_launch(hb, wbuf + (size_t)13 * 65536, tr_bsk, aggO,
              N_NODES, HID, HID, 0, stream);  // skip = h@Wsk + bsk (fp32)
  mfma_launch(hb, wbuf + (size_t)10 * 65536, bcat + 2560, xq,
              N_NODES, 768, HID, 2, stream);
  tr_agg<<<WB, 256, 0, stream>>>(xq, indptr, esrc, aggO, tr_ln_g, tr_ln_b, h);

  // --- pooling (sorted batch; scratch overlays xq, now free) -> geb bf16 ---
  graph_bounds<<<(N_NODES + 255) / 256, 256, 0, stream>>>(batch, gptr);
  pool_seg<<<N_GRAPH, 256, 0, stream>>>(h, gptr, geb);

  // --- output proj (MFMA): tbuf = geb @ out_W + out_b ; then LN+GELU ---
  mfma_launch(geb, wbuf + (size_t)14 * 65536, out_b, tbuf,
              N_GRAPH, 512, 512, 0, stream);
  ln_act<<<(N_GRAPH + 3) / 4, 256, 0, stream>>>(tbuf, out_ln_g, out_ln_b,
                                                (float*)d_out, nullptr,
                                                N_GRAPH, 512, 1);
}

// Round 6
// 1169.147 us; speedup vs baseline: 3.1822x; 1.0627x over previous
//
#include <hip/hip_runtime.h>
#include <math.h>

#define N_NODES 50000
#define N_EDGES 800000
#define N_GRAPH 2000
#define F_INPUT 34
#define HID 256
#define NLAYER 5

typedef __attribute__((ext_vector_type(8))) short short8;
typedef __attribute__((ext_vector_type(4))) float float4v;

// ---------- helpers ----------
__device__ __forceinline__ float gelu_f(float x) {
  return 0.5f * x * (1.0f + erff(x * 0.70710678118654752440f));
}
__device__ __forceinline__ unsigned short bfr(float f) {  // fp32 -> bf16 RNE
  unsigned u = __float_as_uint(f);
  return (unsigned short)((u + 0x7fffu + ((u >> 16) & 1u)) >> 16);
}
__device__ __forceinline__ float b2f(unsigned short s) {
  return __uint_as_float(((unsigned)s) << 16);
}
__device__ __forceinline__ float4 ld4bf(const unsigned short* p) {
  ushort4 u = *(const ushort4*)p;
  float4 f;
  f.x = b2f(u.x); f.y = b2f(u.y); f.z = b2f(u.z); f.w = b2f(u.w);
  return f;
}
// async global->LDS, 16B per lane; lds dest = wave-uniform base + lane*16
__device__ __forceinline__ void acp16(const unsigned short* g, unsigned short* l) {
  __builtin_amdgcn_global_load_lds(
      (const __attribute__((address_space(1))) void*)g,
      (__attribute__((address_space(3))) void*)l, 16, 0, 0);
}

// ---------- fp32 GEMM (input embed K=34 only) ----------
__global__ __launch_bounds__(256) void gemm_bias(
    const float* __restrict__ A, const float* __restrict__ B,
    const float* __restrict__ bias, float* __restrict__ C,
    int M, int Nn, int K) {
  __shared__ float As[16][64];
  __shared__ float Bs[16][64];
  int tid = threadIdx.x;
  int tx = tid & 15, ty = tid >> 4;
  int row0 = blockIdx.y * 64;
  int col0 = blockIdx.x * 64;
  float acc[4][4] = {};
  int a_r = tid >> 2;
  int a_c = (tid & 3) * 4;
  int b_r = tid >> 4;
  int b_c = (tid & 15) * 4;

  for (int k0 = 0; k0 < K; k0 += 16) {
    int ar = row0 + a_r;
#pragma unroll
    for (int i = 0; i < 4; ++i) {
      int kc = k0 + a_c + i;
      As[a_c + i][a_r] = (ar < M && kc < K) ? A[(long)ar * K + kc] : 0.f;
    }
    int bk = k0 + b_r;
    if (bk < K) {
      float4 bv = *(const float4*)&B[(long)bk * Nn + col0 + b_c];
      Bs[b_r][b_c + 0] = bv.x; Bs[b_r][b_c + 1] = bv.y;
      Bs[b_r][b_c + 2] = bv.z; Bs[b_r][b_c + 3] = bv.w;
    } else {
      Bs[b_r][b_c + 0] = 0.f; Bs[b_r][b_c + 1] = 0.f;
      Bs[b_r][b_c + 2] = 0.f; Bs[b_r][b_c + 3] = 0.f;
    }
    __syncthreads();
#pragma unroll
    for (int kk = 0; kk < 16; ++kk) {
      float4 a = *(const float4*)&As[kk][ty * 4];
      float4 b = *(const float4*)&Bs[kk][tx * 4];
      float av[4] = {a.x, a.y, a.z, a.w};
      float bv[4] = {b.x, b.y, b.z, b.w};
#pragma unroll
      for (int i = 0; i < 4; ++i)
#pragma unroll
        for (int j = 0; j < 4; ++j) acc[i][j] += av[i] * bv[j];
    }
    __syncthreads();
  }
  float4 bi = *(const float4*)&bias[col0 + tx * 4];
  float bia[4] = {bi.x, bi.y, bi.z, bi.w};
#pragma unroll
  for (int i = 0; i < 4; ++i) {
    int r = row0 + ty * 4 + i;
    if (r < M) {
      float4 o;
      o.x = acc[i][0] + bia[0]; o.y = acc[i][1] + bia[1];
      o.z = acc[i][2] + bia[2]; o.w = acc[i][3] + bia[3];
      *(float4*)&C[(long)r * Nn + col0 + tx * 4] = o;
    }
  }
}

// ---------- bf16 MFMA GEMM (m97-style async LDS staging) ----------
// A: [M][K] bf16 ; Bt: [Nn][K] bf16 ; bias fp32.
// flags: bit1 = write bf16 (LDS-coalesced epilogue), else fp32.
__global__ __launch_bounds__(256) void gemm_mfma(
    const unsigned short* __restrict__ A, const unsigned short* __restrict__ Bt,
    const float* __restrict__ bias, void* __restrict__ Cv,
    int M, int Nn, int K, int flags) {
  __shared__ unsigned short smem[12288];  // As[128][32]@0, Bs@4096; epilogue overlay
  unsigned short* As = smem;
  unsigned short* Bs = smem + 4096;
  int tid = threadIdx.x;
  int wave = tid >> 6, lane = tid & 63;
  int row0 = blockIdx.y * 128;
  int col0 = blockIdx.x * 128;
  int wm0 = (wave >> 1) * 64;
  int wn0 = (wave & 1) * 64;
  int q = lane >> 4;
  int ln = lane & 15;

  // staging geometry: per wave, 2 issues of 64 lanes x 16B = rows [w*16+t*64, +16)
  int srow = wave * 16 + (lane >> 2);
  int scol = (lane & 3) * 8;
  int ra0 = min(row0 + srow, M - 1);
  int ra1 = min(row0 + srow + 64, M - 1);
  const unsigned short* pa0 = A + (size_t)ra0 * K + scol;
  const unsigned short* pa1 = A + (size_t)ra1 * K + scol;
  const unsigned short* pb0 = Bt + (size_t)(col0 + srow) * K + scol;
  const unsigned short* pb1 = Bt + (size_t)(col0 + srow + 64) * K + scol;
  unsigned short* la0 = As + wave * 512;
  unsigned short* la1 = As + wave * 512 + 2048;
  unsigned short* lb0 = Bs + wave * 512;
  unsigned short* lb1 = Bs + wave * 512 + 2048;

  float4v acc[4][4];
#pragma unroll
  for (int i = 0; i < 4; ++i)
#pragma unroll
    for (int j = 0; j < 4; ++j) acc[i][j] = (float4v)0.f;

  for (int k0 = 0; k0 < K; k0 += 32) {
    acp16(pa0 + k0, la0);
    acp16(pa1 + k0, la1);
    acp16(pb0 + k0, lb0);
    acp16(pb1 + k0, lb1);
    __syncthreads();
    short8 af[4], bf[4];
#pragma unroll
    for (int i = 0; i < 4; ++i)
      af[i] = *(const short8*)&As[(wm0 + i * 16 + ln) * 32 + q * 8];
#pragma unroll
    for (int j = 0; j < 4; ++j)
      bf[j] = *(const short8*)&Bs[(wn0 + j * 16 + ln) * 32 + q * 8];
#pragma unroll
    for (int i = 0; i < 4; ++i)
#pragma unroll
      for (int j = 0; j < 4; ++j)
        acc[i][j] = __builtin_amdgcn_mfma_f32_16x16x32_bf16(af[i], bf[j], acc[i][j], 0, 0, 0);
    __syncthreads();
  }
  int rb = (lane >> 4) * 4;
  if (flags & 2) {
    // LDS-transposed coalesced bf16 epilogue: per-wave 64x64 tile in 2 passes
    unsigned short* Cb = (unsigned short*)Cv;
    unsigned short* eb = smem + wave * 2560;  // 64 rows x stride 40
#pragma unroll
    for (int p = 0; p < 2; ++p) {
#pragma unroll
      for (int jj = 0; jj < 2; ++jj) {
        int j = p * 2 + jj;
        float bv = bias[col0 + wn0 + j * 16 + ln];
#pragma unroll
        for (int i = 0; i < 4; ++i)
#pragma unroll
          for (int r = 0; r < 4; ++r)
            eb[(i * 16 + rb + r) * 40 + jj * 16 + ln] = bfr(acc[i][j][r] + bv);
      }
      int grow = row0 + wm0 + lane;
      uint4 w0 = *(uint4*)&eb[lane * 40 + 0];
      uint4 w1 = *(uint4*)&eb[lane * 40 + 8];
      uint4 w2 = *(uint4*)&eb[lane * 40 + 16];
      uint4 w3 = *(uint4*)&eb[lane * 40 + 24];
      if (grow < M) {
        unsigned short* dst = Cb + (size_t)grow * Nn + col0 + wn0 + p * 32;
        *(uint4*)&dst[0] = w0;
        *(uint4*)&dst[8] = w1;
        *(uint4*)&dst[16] = w2;
        *(uint4*)&dst[24] = w3;
      }
    }
  } else {
    float* C = (float*)Cv;
#pragma unroll
    for (int j = 0; j < 4; ++j) {
      int col = col0 + wn0 + j * 16 + ln;
      float bv = bias[col];
#pragma unroll
      for (int i = 0; i < 4; ++i)
#pragma unroll
        for (int r = 0; r < 4; ++r) {
          int row = row0 + wm0 + i * 16 + rb + r;
          if (row < M) C[(size_t)row * Nn + col] = acc[i][j][r] + bv;
        }
    }
  }
}

// ---------- weight prep: Wt_bf16[n][k] = bf16(W[k][n]) ----------
// slots: 2l=Wl_l, 2l+1=Wr_l (l<5); 10=q, 11=k, 12=v, 13=skip
__global__ __launch_bounds__(256) void prep_w(
    const float* __restrict__ Wl, const float* __restrict__ Wr,
    const float* __restrict__ Wq, const float* __restrict__ Wk,
    const float* __restrict__ Wv, const float* __restrict__ Wsk,
    unsigned short* __restrict__ out) {
  __shared__ float t[32][33];
  int m = blockIdx.z;
  const float* W = (m < 10) ? (((m & 1) ? Wr : Wl) + (size_t)(m >> 1) * 65536)
                 : (m == 10) ? Wq : (m == 11) ? Wk : (m == 12) ? Wv : Wsk;
  int k0 = blockIdx.y * 32, n0 = blockIdx.x * 32;
  int r = threadIdx.x >> 5, c = threadIdx.x & 31;
  for (int rr = r; rr < 32; rr += 8)
    t[rr][c] = W[(size_t)(k0 + rr) * HID + n0 + c];
  __syncthreads();
  unsigned short* o = out + (size_t)m * 65536;
  for (int rr = r; rr < 32; rr += 8)
    o[(size_t)(n0 + rr) * HID + k0 + c] = bfr(t[c][rr]);
}

// out_W [512][512] -> bf16 transpose
__global__ __launch_bounds__(256) void prep_wout(const float* __restrict__ W,
                                                 unsigned short* __restrict__ o) {
  __shared__ float t[32][33];
  int k0 = blockIdx.y * 32, n0 = blockIdx.x * 32;
  int r = threadIdx.x >> 5, c = threadIdx.x & 31;
  for (int rr = r; rr < 32; rr += 8)
    t[rr][c] = W[(size_t)(k0 + rr) * 512 + n0 + c];
  __syncthreads();
  for (int rr = r; rr < 32; rr += 8)
    o[(size_t)(n0 + rr) * 512 + k0 + c] = bfr(t[c][rr]);
}

// concat biases: [5][512] = bl|br per layer, then [768] = bq|bk|bv
__global__ __launch_bounds__(256) void prep_bias(
    const float* __restrict__ bl, const float* __restrict__ br,
    const float* __restrict__ bq, const float* __restrict__ bk,
    const float* __restrict__ bv, float* __restrict__ out) {
  int i = blockIdx.x * 256 + threadIdx.x;
  if (i < 2560) {
    int l = i >> 9, c = i & 511;
    out[i] = (c < 256) ? bl[l * 256 + c] : br[l * 256 + (c - 256)];
  } else if (i < 3328) {
    int j = i - 2560;
    out[i] = (j < 256) ? bq[j] : (j < 512) ? bk[j - 256] : bv[j - 512];
  }
}

// ---------- LayerNorm standalone (embed + final out) ----------
__global__ __launch_bounds__(256) void ln_act(
    const float* __restrict__ in, const float* __restrict__ gam,
    const float* __restrict__ bet, float* __restrict__ out,
    unsigned short* __restrict__ outb,
    int n_rows, int width, int do_gelu) {
  int wid = blockIdx.x * 4 + (threadIdx.x >> 6);
  int lane = threadIdx.x & 63;
  if (wid >= n_rows) return;
  int chunks = width >> 8;
  float4 v[2];
  float s = 0.f;
  for (int c = 0; c < chunks; ++c) {
    int off = c * 256 + lane * 4;
    float4 t = *(const float4*)&in[(size_t)wid * width + off];
    v[c] = t;
    s += t.x + t.y + t.z + t.w;
  }
  for (int o = 1; o < 64; o <<= 1) s += __shfl_xor(s, o);
  float mean = s / (float)width;
  float vs = 0.f;
  for (int c = 0; c < chunks; ++c) {
    float dx = v[c].x - mean, dy = v[c].y - mean, dz = v[c].z - mean, dw = v[c].w - mean;
    vs += dx * dx + dy * dy + dz * dz + dw * dw;
  }
  for (int o = 1; o < 64; o <<= 1) vs += __shfl_xor(vs, o);
  float inv = rsqrtf(vs / (float)width + 1e-5f);
  for (int c = 0; c < chunks; ++c) {
    int off = c * 256 + lane * 4;
    float4 g4 = *(const float4*)&gam[off];
    float4 b4 = *(const float4*)&bet[off];
    float y[4] = {(v[c].x - mean) * inv * g4.x + b4.x,
                  (v[c].y - mean) * inv * g4.y + b4.y,
                  (v[c].z - mean) * inv * g4.z + b4.z,
                  (v[c].w - mean) * inv * g4.w + b4.w};
    if (do_gelu) {
#pragma unroll
      for (int i = 0; i < 4; ++i) y[i] = gelu_f(y[i]);
    }
    size_t idx = (size_t)wid * width + off;
    float4 o4 = {y[0], y[1], y[2], y[3]};
    *(float4*)&out[idx] = o4;
    if (outb) {
      ushort4 ob = {bfr(y[0]), bfr(y[1]), bfr(y[2]), bfr(y[3])};
      *(ushort4*)&outb[idx] = ob;
    }
  }
}

// ---------- CSR build (two-level scan) ----------
__global__ __launch_bounds__(256) void edge_count(const int* __restrict__ ei,
                                                  int* __restrict__ counts) {
  int e = blockIdx.x * 256 + threadIdx.x;
  if (e < N_EDGES) atomicAdd(&counts[ei[N_EDGES + e]], 1);
}

__global__ __launch_bounds__(1024) void scan1(const int* __restrict__ counts,
                                              int* __restrict__ indptr,
                                              int* __restrict__ bsums, int n) {
  __shared__ int sm[1024];
  int tid = threadIdx.x;
  int i = blockIdx.x * 1024 + tid;
  int v = (i < n) ? counts[i] : 0;
  sm[tid] = v;
  __syncthreads();
  for (int off = 1; off < 1024; off <<= 1) {
    int t = (tid >= off) ? sm[tid - off] : 0;
    __syncthreads();
    sm[tid] += t;
    __syncthreads();
  }
  if (i < n) indptr[i] = sm[tid] - v;  // block-local exclusive
  if (tid == 1023) bsums[blockIdx.x] = sm[1023];
}

__global__ void scan2(int* __restrict__ bsums, int nb) {
  if (threadIdx.x == 0 && blockIdx.x == 0) {
    int acc = 0;
    for (int i = 0; i < nb; ++i) { int t = bsums[i]; bsums[i] = acc; acc += t; }
  }
}

__global__ __launch_bounds__(256) void scan3(const int* __restrict__ bsums,
                                             int* __restrict__ indptr,
                                             int* __restrict__ cursor, int n) {
  int i = blockIdx.x * 256 + threadIdx.x;
  if (i < n) {
    int v = indptr[i] + bsums[i >> 10];
    indptr[i] = v;
    cursor[i] = v;
  }
  if (i == 0) indptr[n] = N_EDGES;
}

__global__ __launch_bounds__(256) void edge_scatter(const int* __restrict__ ei,
                                                    int* __restrict__ cursor,
                                                    int* __restrict__ esrc) {
  int e = blockIdx.x * 256 + threadIdx.x;
  if (e < N_EDGES) {
    int d = ei[N_EDGES + e];
    int p = atomicAdd(&cursor[d], 1);
    esrc[p] = ei[e];
  }
}

// ---------- GATv2 agg + bias + LN + GELU + residual (fused, branchless) ----------
// xlr[N][512] bf16 rows = [xl|xr]; writes h (fp32) and hb (bf16).
// Softmax anchored on self-loop score (shift-invariant; scores O(1), clamp +60).
#define GAT_EDGE(f)                                                        \
  {                                                                        \
    float ex = f.x + xri.x; ex = ex > 0.f ? ex : 0.2f * ex;                \
    float ey = f.y + xri.y; ey = ey > 0.f ? ey : 0.2f * ey;                \
    float ez = f.z + xri.z; ez = ez > 0.f ? ez : 0.2f * ez;                \
    float ew = f.w + xri.w; ew = ew > 0.f ? ew : 0.2f * ew;                \
    float p = ex * a4.x + ey * a4.y + ez * a4.z + ew * a4.w;               \
    p += __shfl_xor(p, 1); p += __shfl_xor(p, 2); p += __shfl_xor(p, 4);   \
    float wgt = __expf(fminf(p - m0, 60.f));                               \
    ax += wgt * f.x; ay += wgt * f.y; az += wgt * f.z; aw += wgt * f.w;    \
    lsum += wgt;                                                           \
  }

__global__ __launch_bounds__(256) void gat_agg(
    const unsigned short* __restrict__ xlr, const float* __restrict__ att,
    const int* __restrict__ indptr, const int* __restrict__ esrc,
    const float* __restrict__ pre_bias, const float* __restrict__ gam,
    const float* __restrict__ bet, float* __restrict__ h,
    unsigned short* __restrict__ hb) {
  int wid = blockIdx.x * 4 + (threadIdx.x >> 6);
  int lane = threadIdx.x & 63;
  if (wid >= N_NODES) return;
  float4 xri = ld4bf(&xlr[(size_t)wid * 512 + 256 + lane * 4]);
  float4 a4 = *(const float4*)&att[lane * 4];
  int beg = indptr[wid], end = indptr[wid + 1];

  float m0, lsum, ax, ay, az, aw;
  {  // self loop = softmax anchor
    float4 f = ld4bf(&xlr[(size_t)wid * 512 + lane * 4]);
    float ex = f.x + xri.x; ex = ex > 0.f ? ex : 0.2f * ex;
    float ey = f.y + xri.y; ey = ey > 0.f ? ey : 0.2f * ey;
    float ez = f.z + xri.z; ez = ez > 0.f ? ez : 0.2f * ez;
    float ew = f.w + xri.w; ew = ew > 0.f ? ew : 0.2f * ew;
    float p = ex * a4.x + ey * a4.y + ez * a4.z + ew * a4.w;
    p += __shfl_xor(p, 1); p += __shfl_xor(p, 2); p += __shfl_xor(p, 4);
    m0 = p; lsum = 1.f;
    ax = f.x; ay = f.y; az = f.z; aw = f.w;
  }
  int e = beg;
  for (; e + 3 < end; e += 4) {  // 4 gathers in flight
    int j0 = esrc[e], j1 = esrc[e + 1], j2 = esrc[e + 2], j3 = esrc[e + 3];
    float4 f0 = ld4bf(&xlr[(size_t)j0 * 512 + lane * 4]);
    float4 f1 = ld4bf(&xlr[(size_t)j1 * 512 + lane * 4]);
    float4 f2 = ld4bf(&xlr[(size_t)j2 * 512 + lane * 4]);
    float4 f3 = ld4bf(&xlr[(size_t)j3 * 512 + lane * 4]);
    GAT_EDGE(f0); GAT_EDGE(f1); GAT_EDGE(f2); GAT_EDGE(f3);
  }
  for (; e < end; ++e) {
    int j = esrc[e];
    float4 f = ld4bf(&xlr[(size_t)j * 512 + lane * 4]);
    GAT_EDGE(f);
  }
  float inv = 1.f / (lsum + 1e-16f);
  float4 pb = *(const float4*)&pre_bias[lane * 4];
  float y0 = ax * inv + pb.x, y1 = ay * inv + pb.y;
  float y2 = az * inv + pb.z, y3 = aw * inv + pb.w;
  // LN over 256
  float s = y0 + y1 + y2 + y3;
  for (int o = 1; o < 64; o <<= 1) s += __shfl_xor(s, o);
  float mean = s * (1.f / 256.f);
  float d0 = y0 - mean, d1 = y1 - mean, d2 = y2 - mean, d3 = y3 - mean;
  float vs = d0 * d0 + d1 * d1 + d2 * d2 + d3 * d3;
  for (int o = 1; o < 64; o <<= 1) vs += __shfl_xor(vs, o);
  float inv2 = rsqrtf(vs * (1.f / 256.f) + 1e-5f);
  float4 g4 = *(const float4*)&gam[lane * 4];
  float4 b4 = *(const float4*)&bet[lane * 4];
  y0 = gelu_f(d0 * inv2 * g4.x + b4.x);
  y1 = gelu_f(d1 * inv2 * g4.y + b4.y);
  y2 = gelu_f(d2 * inv2 * g4.z + b4.z);
  y3 = gelu_f(d3 * inv2 * g4.w + b4.w);
  size_t idx = (size_t)wid * HID + lane * 4;
  float4 r4 = *(const float4*)&h[idx];
  y0 += r4.x; y1 += r4.y; y2 += r4.z; y3 += r4.w;
  float4 o4 = {y0, y1, y2, y3};
  *(float4*)&h[idx] = o4;
  ushort4 ob = {bfr(y0), bfr(y1), bfr(y2), bfr(y3)};
  *(ushort4*)&hb[idx] = ob;
}

// ---------- TransformerConv agg + skip + LN + residual (fused, branchless) ----------
// qkv[N][768] bf16 rows = [q|k|v]; skipb[N][256] bf16.
#define TR_EDGE(kj, vj)                                                    \
  {                                                                        \
    float p = qi.x * kj.x + qi.y * kj.y + qi.z * kj.z + qi.w * kj.w;       \
    p += __shfl_xor(p, 1); p += __shfl_xor(p, 2); p += __shfl_xor(p, 4);   \
    float wgt = __expf(fminf(p * scale, 60.f));                            \
    ax += wgt * vj.x; ay += wgt * vj.y; az += wgt * vj.z; aw += wgt * vj.w;\
    lsum += wgt;                                                           \
  }

__global__ __launch_bounds__(256) void tr_agg(
    const unsigned short* __restrict__ qkv, const int* __restrict__ indptr,
    const int* __restrict__ esrc, const unsigned short* __restrict__ skipb,
    const float* __restrict__ gam, const float* __restrict__ bet,
    float* __restrict__ h) {
  int wid = blockIdx.x * 4 + (threadIdx.x >> 6);
  int lane = threadIdx.x & 63;
  if (wid >= N_NODES) return;
  float4 qi = ld4bf(&qkv[(size_t)wid * 768 + lane * 4]);
  int beg = indptr[wid], end = indptr[wid + 1];
  float lsum = 0.f;
  float ax = 0.f, ay = 0.f, az = 0.f, aw = 0.f;
  const float scale = 0.17677669529663687f;
  int e = beg;
  for (; e + 1 < end; e += 2) {  // 4 gathers in flight
    int j0 = esrc[e], j1 = esrc[e + 1];
    float4 k0 = ld4bf(&qkv[(size_t)j0 * 768 + 256 + lane * 4]);
    float4 v0 = ld4bf(&qkv[(size_t)j0 * 768 + 512 + lane * 4]);
    float4 k1 = ld4bf(&qkv[(size_t)j1 * 768 + 256 + lane * 4]);
    float4 v1 = ld4bf(&qkv[(size_t)j1 * 768 + 512 + lane * 4]);
    TR_EDGE(k0, v0); TR_EDGE(k1, v1);
  }
  if (e < end) {
    int j = esrc[e];
    float4 kj = ld4bf(&qkv[(size_t)j * 768 + 256 + lane * 4]);
    float4 vj = ld4bf(&qkv[(size_t)j * 768 + 512 + lane * 4]);
    TR_EDGE(kj, vj);
  }
  float inv = 1.f / (lsum + 1e-16f);
  size_t idx = (size_t)wid * HID + lane * 4;
  float4 sk = ld4bf(&skipb[idx]);
  float y0 = ax * inv + sk.x, y1 = ay * inv + sk.y;
  float y2 = az * inv + sk.z, y3 = aw * inv + sk.w;
  // LN over 256 (no gelu)
  float s = y0 + y1 + y2 + y3;
  for (int o = 1; o < 64; o <<= 1) s += __shfl_xor(s, o);
  float mean = s * (1.f / 256.f);
  float d0 = y0 - mean, d1 = y1 - mean, d2 = y2 - mean, d3 = y3 - mean;
  float vs = d0 * d0 + d1 * d1 + d2 * d2 + d3 * d3;
  for (int o = 1; o < 64; o <<= 1) vs += __shfl_xor(vs, o);
  float inv2 = rsqrtf(vs * (1.f / 256.f) + 1e-5f);
  float4 g4 = *(const float4*)&gam[lane * 4];
  float4 b4 = *(const float4*)&bet[lane * 4];
  float4 r4 = *(const float4*)&h[idx];
  float4 o4;
  o4.x = r4.x + d0 * inv2 * g4.x + b4.x;
  o4.y = r4.y + d1 * inv2 * g4.y + b4.y;
  o4.z = r4.z + d2 * inv2 * g4.z + b4.z;
  o4.w = r4.w + d3 * inv2 * g4.w + b4.w;
  *(float4*)&h[idx] = o4;
}

// ---------- pooling over sorted batch ----------
__global__ __launch_bounds__(256) void graph_bounds(const int* __restrict__ batch,
                                                    int* __restrict__ gptr) {
  int i = blockIdx.x * 256 + threadIdx.x;
  if (i >= N_NODES) return;
  int b0 = batch[i];
  if (i == 0)
    for (int g = 0; g <= b0; ++g) gptr[g] = 0;
  int b1 = (i + 1 < N_NODES) ? batch[i + 1] : N_GRAPH;
  for (int g = b0 + 1; g <= b1; ++g) gptr[g] = i + 1;
}

__global__ __launch_bounds__(256) void pool_seg(
    const float* __restrict__ h, const int* __restrict__ gptr,
    unsigned short* __restrict__ geb) {
  int g = blockIdx.x, c = threadIdx.x;
  int s = gptr[g], e = gptr[g + 1];
  float sum = 0.f, mx = -INFINITY;
  for (int r = s; r < e; ++r) {
    float vv = h[(size_t)r * HID + c];
    sum += vv;
    mx = fmaxf(mx, vv);
  }
  int cnt = e - s;
  geb[(size_t)g * 512 + c] = bfr(sum / (float)max(cnt, 1));
  geb[(size_t)g * 512 + 256 + c] = bfr(cnt ? mx : 0.f);
}

// ---------- host ----------
static inline void mfma_launch(const unsigned short* A, const unsigned short* Bt,
                               const float* bias, void* C, int M, int Nn, int K,
                               int flags, hipStream_t s) {
  dim3 grid(Nn / 128, (M + 127) / 128);
  gemm_mfma<<<grid, 256, 0, s>>>(A, Bt, bias, C, M, Nn, K, flags);
}

extern "C" void kernel_launch(void* const* d_in, const int* in_sizes, int n_in,
                              void* d_out, int out_size, void* d_ws, size_t ws_size,
                              hipStream_t stream) {
  const float* x       = (const float*)d_in[0];
  const int*   ei      = (const int*)d_in[1];
  const int*   batch   = (const int*)d_in[2];
  const float* in_W    = (const float*)d_in[3];
  const float* in_b    = (const float*)d_in[4];
  const float* in_ln_g = (const float*)d_in[5];
  const float* in_ln_b = (const float*)d_in[6];
  const float* gat_Wl  = (const float*)d_in[7];
  const float* gat_bl  = (const float*)d_in[8];
  const float* gat_Wr  = (const float*)d_in[9];
  const float* gat_br  = (const float*)d_in[10];
  const float* gat_att = (const float*)d_in[11];
  const float* gat_bias= (const float*)d_in[12];
  const float* gat_ln_g= (const float*)d_in[13];
  const float* gat_ln_b= (const float*)d_in[14];
  const float* tr_Wq   = (const float*)d_in[15];
  const float* tr_bq   = (const float*)d_in[16];
  const float* tr_Wk   = (const float*)d_in[17];
  const float* tr_bk   = (const float*)d_in[18];
  const float* tr_Wv   = (const float*)d_in[19];
  const float* tr_bv   = (const float*)d_in[20];
  const float* tr_Wsk  = (const float*)d_in[21];
  const float* tr_bsk  = (const float*)d_in[22];
  const float* tr_ln_g = (const float*)d_in[23];
  const float* tr_ln_b = (const float*)d_in[24];
  const float* out_W   = (const float*)d_in[25];
  const float* out_b   = (const float*)d_in[26];
  const float* out_ln_g= (const float*)d_in[27];
  const float* out_ln_b= (const float*)d_in[28];

  // ---- workspace (256B-aligned) ----
  char* w = (char*)d_ws;
  auto take = [&](size_t bytes) -> char* {
    char* p = w;
    w += (bytes + 255) & ~(size_t)255;
    return p;
  };
  const size_t NB = (size_t)N_NODES * HID * sizeof(float);
  float* h    = (float*)take(NB);                                    // 51.2 MB
  float* aggO = (float*)take(NB);                                    // embed tmp / bf16 skip
  unsigned short* hb  = (unsigned short*)take((size_t)N_NODES * HID * 2);   // 25.6 MB
  unsigned short* xq  = (unsigned short*)take((size_t)N_NODES * 768 * 2);   // 76.8 MB
  unsigned short* wbuf= (unsigned short*)take((size_t)(14 * 65536 + 262144) * 2);
  float* bcat = (float*)take(3328 * sizeof(float));
  int* indptr = (int*)take((N_NODES + 1) * sizeof(int));
  int* cursor = (int*)take(N_NODES * sizeof(int));
  int* counts = (int*)take(N_NODES * sizeof(int));
  int* esrc   = (int*)take(N_EDGES * sizeof(int));
  int* bsums  = (int*)take(64 * sizeof(int));
  unsigned short* skipb = (unsigned short*)aggO;  // bf16 skip overlays aggO
  // pool/output scratch overlays xq (free after tr_agg)
  char* w2 = (char*)xq;
  auto take2 = [&](size_t bytes) -> char* {
    char* p = w2;
    w2 += (bytes + 255) & ~(size_t)255;
    return p;
  };
  int* gptr = (int*)take2((N_GRAPH + 1) * sizeof(int));
  unsigned short* geb = (unsigned short*)take2((size_t)N_GRAPH * 512 * 2);
  float* tbuf = (float*)take2((size_t)N_GRAPH * 512 * sizeof(float));

  const int EB = (N_EDGES + 255) / 256;
  const int WB = (N_NODES + 3) / 4;
  const int NSB = (N_NODES + 1023) / 1024;

  // --- weight/bias prep ---
  {
    dim3 g(8, 8, 14);
    prep_w<<<g, 256, 0, stream>>>(gat_Wl, gat_Wr, tr_Wq, tr_Wk, tr_Wv, tr_Wsk, wbuf);
    dim3 g2(16, 16);
    prep_wout<<<g2, 256, 0, stream>>>(out_W, wbuf + (size_t)14 * 65536);
    prep_bias<<<13, 256, 0, stream>>>(gat_bl, gat_br, tr_bq, tr_bk, tr_bv, bcat);
  }

  // --- CSR (dst-sorted), two-level scan ---
  hipMemsetAsync(counts, 0, N_NODES * sizeof(int), stream);
  edge_count<<<EB, 256, 0, stream>>>(ei, counts);
  scan1<<<NSB, 1024, 0, stream>>>(counts, indptr, bsums, N_NODES);
  scan2<<<1, 64, 0, stream>>>(bsums, NSB);
  scan3<<<(N_NODES + 255) / 256, 256, 0, stream>>>(bsums, indptr, cursor, N_NODES);
  edge_scatter<<<EB, 256, 0, stream>>>(ei, cursor, esrc);

  // --- input embed: h = gelu(LN(x @ in_W + in_b)), hb = bf16(h) ---
  {
    dim3 grid(HID / 64, (N_NODES + 63) / 64);
    gemm_bias<<<grid, 256, 0, stream>>>(x, in_W, in_b, aggO, N_NODES, HID, F_INPUT);
  }
  ln_act<<<WB, 256, 0, stream>>>(aggO, in_ln_g, in_ln_b, h, hb, N_NODES, HID, 1);

  // --- 5 GATv2 layers: fused Wl|Wr GEMM -> xq[N][512] bf16; fused agg+LN ---
  for (int l = 0; l < NLAYER; ++l) {
    mfma_launch(hb, wbuf + (size_t)(2 * l) * 65536, bcat + l * 512, xq,
                N_NODES, 512, HID, 2, stream);
    gat_agg<<<WB, 256, 0, stream>>>(xq, gat_att + l * HID, indptr, esrc,
                                    gat_bias + l * HID, gat_ln_g + l * HID,
                                    gat_ln_b + l * HID, h, hb);
  }

  // --- TransformerConv: bf16 skip GEMM, fused q|k|v GEMM, fused agg+LN ---
  mfma_launch(hb, wbuf + (size_t)13 * 65536, tr_bsk, skipb,
              N_NODES, HID, HID, 2, stream);  // skip = bf16(h@Wsk + bsk)
  mfma_launch(hb, wbuf + (size_t)10 * 65536, bcat + 2560, xq,
              N_NODES, 768, HID, 2, stream);
  tr_agg<<<WB, 256, 0, stream>>>(xq, indptr, esrc, skipb, tr_ln_g, tr_ln_b, h);

  // --- pooling (sorted batch; scratch overlays xq, now free) -> geb bf16 ---
  graph_bounds<<<(N_NODES + 255) / 256, 256, 0, stream>>>(batch, gptr);
  pool_seg<<<N_GRAPH, 256, 0, stream>>>(h, gptr, geb);

  // --- output proj (MFMA): tbuf = geb @ out_W + out_b ; then LN+GELU ---
  mfma_launch(geb, wbuf + (size_t)14 * 65536, out_b, tbuf,
              N_GRAPH, 512, 512, 0, stream);
  ln_act<<<(N_GRAPH + 3) / 4, 256, 0, stream>>>(tbuf, out_ln_g, out_ln_b,
                                                (float*)d_out, nullptr,
                                                N_GRAPH, 512, 1);
}